// Round 6
// baseline (341.829 us; speedup 1.0000x reference)
//
#include <hip/hip_runtime.h>
#include <math.h>

typedef unsigned short u16;
typedef unsigned int u32;
typedef __attribute__((ext_vector_type(8))) short bf16x8;
typedef __attribute__((ext_vector_type(4))) float f32x4;

constexpr int BB   = 8;
constexpr int DIMC = 128;
constexpr int HH   = 128;
constexpr int WW   = 128;
constexpr int NTOK = HH * WW;       // 16384
constexpr int QKD  = 128;
constexpr int MLPD = 256;
constexpr int NTm  = 8;
constexpr int GSZ  = 128;
constexpr int NGRP = NTOK / GSZ;    // 128
constexpr size_t BIG = 16777216;    // 8*16384*128 elements

__device__ __forceinline__ float gelu_f(float v) {
    return 0.5f * v * (1.0f + erff(v * 0.70710678118654752440f));
}
__device__ __forceinline__ float b2f(u16 u) {
    return __uint_as_float(((u32)u) << 16);
}
__device__ __forceinline__ u16 f2b(float f) {
    u32 x = __float_as_uint(f);
    return (u16)((x + 0x7fffu + ((x >> 16) & 1u)) >> 16);
}
__device__ __forceinline__ float ulo(u32 u) { return __uint_as_float(u << 16); }
__device__ __forceinline__ float uhi(u32 u) { return __uint_as_float(u & 0xffff0000u); }

// ---------------- prep: normalized means (fp32), global K (bf16), global V^T (bf16) ----------------
__global__ __launch_bounds__(128) void k_prep(const float* __restrict__ means,
        const float* __restrict__ iwk, const float* __restrict__ iwv,
        float* __restrict__ mhat, u16* __restrict__ kgbb, u16* __restrict__ vgtb) {
    __shared__ float sm[DIMC];
    __shared__ float inv_s;
    int tt = blockIdx.x;          // mean row 0..7
    int t = threadIdx.x;          // 0..127
    sm[t] = means[tt * DIMC + t];
    __syncthreads();
    if (t == 0) {
        float s = 0.f;
        for (int c = 0; c < DIMC; c++) s += sm[c] * sm[c];
        inv_s = 1.f / fmaxf(sqrtf(s), 1e-12f);
    }
    __syncthreads();
    mhat[tt * DIMC + t] = sm[t] * inv_s;
    float sk = 0.f, sv = 0.f;
    #pragma unroll 8
    for (int c = 0; c < DIMC; c++) {
        sk = fmaf(sm[c], iwk[t * DIMC + c], sk);
        sv = fmaf(sm[c], iwv[t * DIMC + c], sv);
    }
    kgbb[tt * DIMC + t] = f2b(sk);
    vgtb[(t >> 5) * 256 + (t & 31) * 8 + tt] = f2b(sv);   // [head][dv][8]
}

// ---------------- all weight converts fp32->bf16 in one launch ----------------
__global__ __launch_bounds__(256) void k_cvtall(const float* __restrict__ wq,
        const float* __restrict__ wk, const float* __restrict__ wv,
        const float* __restrict__ fc1, const float* __restrict__ fc2,
        u16* __restrict__ wqkv, u16* __restrict__ fc1b, u16* __restrict__ fc2b) {
    int i = blockIdx.x * 256 + threadIdx.x;
    if (i < 49152) {
        const float* s = (i < 16384) ? wq : (i < 32768 ? wk : wv);
        wqkv[i] = f2b(s[i & 16383]);
    } else if (i < 81920) {
        fc1b[i - 49152] = f2b(fc1[i - 49152]);
    } else if (i < 114688) {
        fc2b[i - 81920] = f2b(fc2[i - 81920]);
    }
}

// ---------------- fused conv1x1 @ wproj ----------------
__global__ __launch_bounds__(256) void k_fuse(const float* __restrict__ c1,
        const float* __restrict__ wp, u16* __restrict__ wf) {
    __shared__ float wpS[DIMC * DIMC];
    int t = threadIdx.x;
    for (int i = t; i < DIMC * DIMC; i += 256) wpS[i] = wp[i];
    __syncthreads();
    int o = blockIdx.x * 2 + (t >> 7);
    int c = t & 127;
    float s = 0.f;
    #pragma unroll 8
    for (int m = 0; m < DIMC; m++) s = fmaf(c1[o * DIMC + m], wpS[m * DIMC + c], s);
    wf[o * DIMC + c] = f2b(s);
}

// ---------------- LN1 + cluster scores + bucket (bf16 xn out), channel-split ----------------
__global__ __launch_bounds__(256) void k_ln1(const float* __restrict__ x,
        const float* __restrict__ lw, const float* __restrict__ lb,
        const float* __restrict__ mhat, u16* __restrict__ xn, int* __restrict__ bucket) {
    __shared__ float smh[NTm * DIMC];     // 4 KB
    __shared__ float lwb[DIMC], lbb[DIMC];
    __shared__ float red[4][64][3];       // sum, sq (+pad -> 2-way max)
    __shared__ float scr[4][64][9];       // partial scores (+pad -> 2-way max)
    const int chunk = blockIdx.x;         // 0..2047
    const int b = chunk >> 8;
    const int n0 = (chunk & 255) << 6;
    const int t = threadIdx.x;
    const int cg = t >> 6, tok = t & 63;
    const int n = n0 + tok;
    const int cbase = cg * 32;
    for (int i = t; i < NTm * DIMC; i += 256) smh[i] = mhat[i];
    if (t < DIMC) { lwb[t] = lw[t]; lbb[t] = lb[t]; }

    const float* xb = x + (size_t)b * DIMC * NTOK + (size_t)cbase * NTOK + n;
    float xv[32];
    float sum = 0.f, sq = 0.f;
    #pragma unroll
    for (int c = 0; c < 32; c++) {
        float v = xb[(size_t)c * NTOK];
        xv[c] = v;
        sum += v; sq += v * v;
    }
    red[cg][tok][0] = sum;
    red[cg][tok][1] = sq;
    __syncthreads();                      // covers smh/lwb staging + red
    float s0 = red[0][tok][0] + red[1][tok][0] + red[2][tok][0] + red[3][tok][0];
    float q0 = red[0][tok][1] + red[1][tok][1] + red[2][tok][1] + red[3][tok][1];
    float mean = s0 * (1.0f / DIMC);
    float var = q0 * (1.0f / DIMC) - mean * mean;
    float rstd = rsqrtf(var + 1e-5f);

    float sc[NTm];
    #pragma unroll
    for (int j = 0; j < NTm; j++) sc[j] = 0.f;
    u32 opk[16];
    #pragma unroll
    for (int c = 0; c < 32; c += 2) {
        float v0 = (xv[c]     - mean) * rstd * lwb[cbase + c]     + lbb[cbase + c];
        float v1 = (xv[c + 1] - mean) * rstd * lwb[cbase + c + 1] + lbb[cbase + c + 1];
        #pragma unroll
        for (int j = 0; j < NTm; j++) {
            sc[j] = fmaf(v0, smh[j * DIMC + cbase + c], sc[j]);
            sc[j] = fmaf(v1, smh[j * DIMC + cbase + c + 1], sc[j]);
        }
        opk[c >> 1] = (u32)f2b(v0) | ((u32)f2b(v1) << 16);
    }
    u16* xnr = xn + ((size_t)b * NTOK + n) * DIMC + cbase;
    *(uint4*)(xnr + 0)  = make_uint4(opk[0],  opk[1],  opk[2],  opk[3]);
    *(uint4*)(xnr + 8)  = make_uint4(opk[4],  opk[5],  opk[6],  opk[7]);
    *(uint4*)(xnr + 16) = make_uint4(opk[8],  opk[9],  opk[10], opk[11]);
    *(uint4*)(xnr + 24) = make_uint4(opk[12], opk[13], opk[14], opk[15]);

    #pragma unroll
    for (int j = 0; j < NTm; j++) scr[cg][tok][j] = sc[j];
    __syncthreads();
    if (cg == 0) {
        float v0 = ((scr[0][tok][0] + scr[1][tok][0]) + (scr[2][tok][0] + scr[3][tok][0]));
        int best = 0; float bv = v0;
        #pragma unroll
        for (int j = 1; j < NTm; j++) {
            float v = ((scr[0][tok][j] + scr[1][tok][j]) + (scr[2][tok][j] + scr[3][tok][j]));
            if (v > bv) { bv = v; best = j; }
        }
        bucket[b * NTOK + n] = best;
    }
}

// ---------------- stable counting sort ----------------
__global__ __launch_bounds__(64) void k_count(const int* __restrict__ bucket, int* __restrict__ cnt) {
    int chunk = blockIdx.x;
    int bk = bucket[(chunk << 6) + threadIdx.x];
    #pragma unroll
    for (int j = 0; j < NTm; j++) {
        unsigned long long m = __ballot(bk == j);
        if (threadIdx.x == 0) cnt[chunk * NTm + j] = (int)__popcll(m);
    }
}

__global__ __launch_bounds__(64) void k_scan(const int* __restrict__ cnt, int* __restrict__ base) {
    __shared__ int sc[256 * NTm];
    __shared__ int bb[NTm], tot[NTm];
    int b = blockIdx.x, t = threadIdx.x;
    for (int i = t; i < 256 * NTm; i += 64) sc[i] = cnt[b * 256 * NTm + i];
    __syncthreads();
    if (t < NTm) {
        int run = 0;
        for (int c = 0; c < 256; c++) {
            int v = sc[c * NTm + t];
            sc[c * NTm + t] = run;
            run += v;
        }
        tot[t] = run;
    }
    __syncthreads();
    if (t == 0) {
        int a = 0;
        for (int j = 0; j < NTm; j++) { bb[j] = a; a += tot[j]; }
    }
    __syncthreads();
    for (int i = t; i < 256 * NTm; i += 64) base[b * 256 * NTm + i] = sc[i] + bb[i & 7];
}

__global__ __launch_bounds__(64) void k_place(const int* __restrict__ bucket,
        const int* __restrict__ base, int* __restrict__ gidx) {
    int chunk = blockIdx.x;
    int lane = threadIdx.x;
    int nf = (chunk << 6) + lane;
    int bk = bucket[nf];
    unsigned long long lower = (1ull << lane) - 1ull;
    int rank = 0;
    #pragma unroll
    for (int j = 0; j < NTm; j++) {
        unsigned long long m = __ballot(bk == j);
        if (bk == j) rank = (int)__popcll(m & lower);
    }
    int b = nf >> 14;
    int pos = base[chunk * NTm + bk] + rank;
    gidx[b * NTOK + pos] = nf & (NTOK - 1);
}

// ---------------- invert permutation: iinv[token] = sorted position (u16) ----------------
__global__ __launch_bounds__(256) void k_inv(const int* __restrict__ gidx, u16* __restrict__ iinv) {
    int i = blockIdx.x * 256 + threadIdx.x;   // 0 .. B*NTOK-1
    int b = i >> 14;
    iinv[((size_t)b << 14) + gidx[i]] = (u16)(i & (NTOK - 1));
}

// ---------------- MFMA bf16 GEMM: C[m][n] = sum_k A[m][k]*W[n][k] ----------------
// AIMG: A is bf16 image-layout [B][KDIM][NTOK] (stage with transpose)
// GATHER: 0 none, 1 int32 index (gidx), 2 u16 index (iinv)
// RES: 0 none, 1 fp32 image resid, 3 bf16 token resid
// STIMG: 1 = image-layout store; CBF: 1 = bf16 store, 0 = fp32
// LN2F: fused LayerNorm epilogue (requires NOUT=128, RES=1, grid.y=1)
// ascale multiplies acc when blockIdx.y==0 (used to pre-scale q)
template<int KDIM, int NOUT, int GATHER, int AIMG, int BIASF, int GELUF, int RES, int STIMG, int CBF, int LN2F>
__global__ __launch_bounds__(256) void g_mfma(const u16* __restrict__ A, const u16* __restrict__ W,
        const float* __restrict__ bias, const void* __restrict__ resid,
        const int* __restrict__ gidx, void* __restrict__ Cout, float ascale,
        const float* __restrict__ lnw, const float* __restrict__ lnb, void* __restrict__ Cout2) {
    __shared__ u16 As[128 * 40];
    __shared__ u16 Ws[128 * 40];
    const int b = blockIdx.z;
    const int m0 = blockIdx.x * 128;
    const int n0 = blockIdx.y * 128;
    const int t = threadIdx.x;
    const int lane = t & 63;
    const int wave = t >> 6;
    const int wm = (wave & 1) * 64;
    const int wn = (wave >> 1) * 64;
    const int srow = t >> 2;
    const int sko = (t & 3) * 8;
    const u16* pA0 = nullptr; const u16* pA1 = nullptr;
    if (!AIMG) {
        int ra0 = m0 + srow, ra1 = m0 + 64 + srow;
        if (GATHER == 1) {
            ra0 = gidx[b * NTOK + ra0];
            ra1 = gidx[b * NTOK + ra1];
        } else if (GATHER == 2) {
            const u16* gi = (const u16*)gidx;
            ra0 = gi[b * NTOK + ra0];
            ra1 = gi[b * NTOK + ra1];
        }
        pA0 = A + ((size_t)b * NTOK + ra0) * KDIM + sko;
        pA1 = A + ((size_t)b * NTOK + ra1) * KDIM + sko;
    }
    const u16* pW0 = W + (size_t)(n0 + srow) * KDIM + sko;
    const u16* pW1 = W + (size_t)(n0 + 64 + srow) * KDIM + sko;

    f32x4 acc[4][4];
    #pragma unroll
    for (int i = 0; i < 4; i++)
        #pragma unroll
        for (int j = 0; j < 4; j++) acc[i][j] = (f32x4){0.f, 0.f, 0.f, 0.f};

    for (int k0 = 0; k0 < KDIM; k0 += 32) {
        uint4 a0, a1, w0, w1;
        u16 e[16];
        if (!AIMG) {
            a0 = *(const uint4*)(pA0 + k0);
            a1 = *(const uint4*)(pA1 + k0);
        } else {
            const int kk2 = t & 31;
            const int tg = t >> 5;
            const u16* src = A + ((size_t)b * KDIM + k0 + kk2) * NTOK + m0 + tg * 16;
            *(uint4*)&e[0] = *(const uint4*)src;
            *(uint4*)&e[8] = *(const uint4*)(src + 8);
        }
        w0 = *(const uint4*)(pW0 + k0);
        w1 = *(const uint4*)(pW1 + k0);
        __syncthreads();
        if (!AIMG) {
            *(uint4*)&As[srow * 40 + sko] = a0;
            *(uint4*)&As[(64 + srow) * 40 + sko] = a1;
        } else {
            const int kk2 = t & 31;
            const int tg = t >> 5;
            #pragma unroll
            for (int j = 0; j < 16; j++) As[(tg * 16 + j) * 40 + kk2] = e[j];
        }
        *(uint4*)&Ws[srow * 40 + sko] = w0;
        *(uint4*)&Ws[(64 + srow) * 40 + sko] = w1;
        __syncthreads();
        bf16x8 af[4], bfv[4];
        #pragma unroll
        for (int i = 0; i < 4; i++)
            af[i] = *(bf16x8*)&As[(wm + i * 16 + (lane & 15)) * 40 + (lane >> 4) * 8];
        #pragma unroll
        for (int j = 0; j < 4; j++)
            bfv[j] = *(bf16x8*)&Ws[(wn + j * 16 + (lane & 15)) * 40 + (lane >> 4) * 8];
        #pragma unroll
        for (int i = 0; i < 4; i++)
            #pragma unroll
            for (int j = 0; j < 4; j++)
                acc[i][j] = __builtin_amdgcn_mfma_f32_16x16x32_bf16(af[i], bfv[j], acc[i][j], 0, 0, 0);
    }

    const int c2 = lane & 15, gq2 = lane >> 4;
    int colj[4];
    #pragma unroll
    for (int j = 0; j < 4; j++) colj[j] = n0 + wn + j * 16 + c2;

    if (LN2F) {
        #pragma unroll
        for (int i = 0; i < 4; i++) {
            int rbase = m0 + wm + i * 16 + gq2 * 4;
            #pragma unroll
            for (int j = 0; j < 4; j++) {
                const float* rf = (const float*)resid;
                float4 rr = *(const float4*)&rf[((size_t)b * NOUT + colj[j]) * NTOK + rbase];
                acc[i][j][0] += rr.x; acc[i][j][1] += rr.y;
                acc[i][j][2] += rr.z; acc[i][j][3] += rr.w;
            }
        }
        __syncthreads();                      // all waves done with As/Ws frag reads
        float* ps = (float*)&As[0];           // [2 halves][128 rows][2] = 2 KB, overlays As
        const int h = wn >> 6;
        float mean_[4][4], rstd_[4][4];
        #pragma unroll
        for (int i = 0; i < 4; i++)
            #pragma unroll
            for (int r = 0; r < 4; r++) {
                float s = 0.f, q = 0.f;
                #pragma unroll
                for (int j = 0; j < 4; j++) { float tv = acc[i][j][r]; s += tv; q += tv * tv; }
                s += __shfl_xor(s, 1, 64); q += __shfl_xor(q, 1, 64);
                s += __shfl_xor(s, 2, 64); q += __shfl_xor(q, 2, 64);
                s += __shfl_xor(s, 4, 64); q += __shfl_xor(q, 4, 64);
                s += __shfl_xor(s, 8, 64); q += __shfl_xor(q, 8, 64);
                if (c2 == 0) {
                    int rl = wm + i * 16 + gq2 * 4 + r;
                    ps[(h * 128 + rl) * 2 + 0] = s;
                    ps[(h * 128 + rl) * 2 + 1] = q;
                }
            }
        __syncthreads();
        #pragma unroll
        for (int i = 0; i < 4; i++)
            #pragma unroll
            for (int r = 0; r < 4; r++) {
                int rl = wm + i * 16 + gq2 * 4 + r;
                float s = ps[rl * 2 + 0] + ps[(128 + rl) * 2 + 0];
                float q = ps[rl * 2 + 1] + ps[(128 + rl) * 2 + 1];
                float mn = s * (1.0f / 128.0f);
                float vr = q * (1.0f / 128.0f) - mn * mn;
                mean_[i][r] = mn;
                rstd_[i][r] = rsqrtf(vr + 1e-5f);
            }
        float lwj[4], lbj[4];
        #pragma unroll
        for (int j = 0; j < 4; j++) { lwj[j] = lnw[colj[j]]; lbj[j] = lnb[colj[j]]; }
        u16* xo = (u16*)Cout;
        u16* mo = (u16*)Cout2;
        #pragma unroll
        for (int i = 0; i < 4; i++) {
            int rbase = m0 + wm + i * 16 + gq2 * 4;
            #pragma unroll
            for (int j = 0; j < 4; j++)
                #pragma unroll
                for (int r = 0; r < 4; r++) {
                    float tv = acc[i][j][r];
                    size_t off = ((size_t)b * NTOK + rbase + r) * NOUT + colj[j];
                    xo[off] = f2b(tv);
                    mo[off] = f2b((tv - mean_[i][r]) * rstd_[i][r] * lwj[j] + lbj[j]);
                }
        }
        return;
    }

    const float smul = (blockIdx.y == 0) ? ascale : 1.0f;
    float bj[4];
    #pragma unroll
    for (int j = 0; j < 4; j++) bj[j] = BIASF ? bias[colj[j]] : 0.f;
    #pragma unroll
    for (int i = 0; i < 4; i++) {
        int rbase = m0 + wm + i * 16 + gq2 * 4;
        #pragma unroll
        for (int j = 0; j < 4; j++) {
            f32x4 v = acc[i][j];
            v[0] *= smul; v[1] *= smul; v[2] *= smul; v[3] *= smul;
            if (BIASF) { v[0] += bj[j]; v[1] += bj[j]; v[2] += bj[j]; v[3] += bj[j]; }
            if (GELUF) { v[0] = gelu_f(v[0]); v[1] = gelu_f(v[1]); v[2] = gelu_f(v[2]); v[3] = gelu_f(v[3]); }
            if (RES == 1) {
                const float* rf = (const float*)resid;
                float4 rr = *(const float4*)&rf[((size_t)b * NOUT + colj[j]) * NTOK + rbase];
                v[0] += rr.x; v[1] += rr.y; v[2] += rr.z; v[3] += rr.w;
            } else if (RES == 3) {
                const u16* rb = (const u16*)resid;
                #pragma unroll
                for (int r = 0; r < 4; r++)
                    v[r] += b2f(rb[((size_t)b * NTOK + rbase + r) * NOUT + colj[j]]);
            }
            if (STIMG) {
                size_t off = ((size_t)b * NOUT + colj[j]) * NTOK + rbase;
                if (CBF) {
                    ushort4 o;
                    o.x = f2b(v[0]); o.y = f2b(v[1]); o.z = f2b(v[2]); o.w = f2b(v[3]);
                    *(ushort4*)((u16*)Cout + off) = o;
                } else {
                    *(float4*)((float*)Cout + off) = make_float4(v[0], v[1], v[2], v[3]);
                }
            } else {
                if (CBF) {
                    #pragma unroll
                    for (int r = 0; r < 4; r++)
                        ((u16*)Cout)[((size_t)b * NTOK + rbase + r) * NOUT + colj[j]] = f2b(v[r]);
                } else {
                    #pragma unroll
                    for (int r = 0; r < 4; r++)
                        ((float*)Cout)[((size_t)b * NTOK + rbase + r) * NOUT + colj[j]] = v[r];
                }
            }
        }
    }
}

// ---------------- MFMA windowed + global attention ----------------
// qk: [B][NTOK][256] bf16 (q prescaled by log2e/sqrt(32)), sorted domain
// vimg: [B][128][NTOK] bf16 image-layout V (sorted token axis) -> V^T staging
// is pure vector load + ds_write_b128 (no scalar transpose).
// Softmax uses exp2f (scale baked into q) -> v_exp_f32 directly, no v_mul.
// block = (group, head-pair, batch); 4 waves: wave = (qhalf<<1) | local-head
__global__ __launch_bounds__(256, 3) void k_attn(const u16* __restrict__ qk,
        const u16* __restrict__ vimg,
        const u16* __restrict__ kgbb, const u16* __restrict__ vgtb,
        u16* __restrict__ outp) {
    __shared__ u16 VT[2][32][264];   // V^T per local head: [dv][key 0..255 local, 256..263 global]
    __shared__ u16 Pb[4][64][40];    // per-wave P buffer [q][key-chunk 32 + pad]
    const int g = blockIdx.x, hp = blockIdx.y, b = blockIdx.z;
    const int t = threadIdx.x;
    const int wave = t >> 6, lane = t & 63;
    const int c = lane & 15, gq = lane >> 4;
    const int lh = wave & 1, head = hp * 2 + lh, qh = wave >> 1;
    const size_t brow = (size_t)b * NTOK;
    const bool lastg = (g == NGRP - 1);

    {   // stage V^T from image-layout vimg: vector loads + b128 LDS writes
        const int dv = t >> 2;        // 0..63 (lh*32 + dv-local)
        const int kc = t & 3;
        const u16* vrow = vimg + ((size_t)(b * 128 + hp * 64 + dv)) * NTOK;
        u16* vtrow = (u16*)&VT[0][0][0] + dv * 264;
        #pragma unroll
        for (int p = 0; p < 8; p++) {
            int chunk = p * 4 + kc;   // 0..31
            int k0 = chunk * 8;       // key base
            uint4 v;
            if (!lastg || k0 < GSZ) {
                v = *(const uint4*)(vrow + g * GSZ + k0);
            } else {
                // last group tail: keys map to reversed tokens
                uint4 r = *(const uint4*)(vrow + NTOK + 120 - k0);
                u16 e[8], o[8];
                *(uint4*)e = r;
                #pragma unroll
                for (int j = 0; j < 8; j++) o[j] = e[7 - j];
                v = *(uint4*)o;
            }
            *(uint4*)(vtrow + k0) = v;
        }
        if (t < 64) {   // global V^T -> keys 256..263
            int l2 = t >> 5, dvg = t & 31;
            uint4 v = *(const uint4*)(vgtb + ((size_t)(hp * 2 + l2) * 32 + dvg) * 8);
            *(uint4*)&VT[l2][dvg][256] = v;
        }
    }

    // prefetch Q, ALL K fragments, and global-K before the barrier
    const int q0 = g * GSZ + qh * 64;
    bf16x8 qf[4];
    #pragma unroll
    for (int nq = 0; nq < 4; nq++)
        qf[nq] = *(const bf16x8*)(qk + (brow + q0 + nq * 16 + c) * 256 + head * 32 + gq * 8);

    const u16* kbp = qk + brow * 256 + 128 + head * 32 + gq * 8;
    bf16x8 kfa[8][2];
    #pragma unroll
    for (int s = 0; s < 8; s++)
        #pragma unroll
        for (int mk = 0; mk < 2; mk++) {
            int kl = s * 32 + mk * 16 + c;
            int pos = (!lastg || kl < GSZ) ? g * GSZ + kl : NTOK - 1 - (kl - GSZ);
            kfa[s][mk] = *(const bf16x8*)(kbp + (size_t)pos * 256);
        }
    bf16x8 kgf = *(const bf16x8*)(kgbb + (c & 7) * 128 + head * 32 + gq * 8);

    __syncthreads();

    f32x4 acc[4][2];
    #pragma unroll
    for (int i = 0; i < 4; i++)
        #pragma unroll
        for (int j = 0; j < 2; j++) acc[i][j] = (f32x4){0.f, 0.f, 0.f, 0.f};
    float lsum[4] = {0.f, 0.f, 0.f, 0.f};

    for (int s = 0; s < 8; s++) {
        // S^T = K x Q^T : lane holds 4 consecutive keys for q-col c
        #pragma unroll
        for (int mk = 0; mk < 2; mk++) {
            #pragma unroll
            for (int nq = 0; nq < 4; nq++) {
                f32x4 st = __builtin_amdgcn_mfma_f32_16x16x32_bf16(kfa[s][mk], qf[nq],
                        (f32x4){0.f, 0.f, 0.f, 0.f}, 0, 0, 0);
                float p0 = exp2f(st[0]), p1 = exp2f(st[1]);
                float p2 = exp2f(st[2]), p3 = exp2f(st[3]);
                lsum[nq] += (p0 + p1) + (p2 + p3);
                u32 r0, r1;
                asm("v_cvt_pk_bf16_f32 %0, %1, %2" : "=v"(r0) : "v"(p0), "v"(p1));
                asm("v_cvt_pk_bf16_f32 %0, %1, %2" : "=v"(r1) : "v"(p2), "v"(p3));
                *(uint2*)&Pb[wave][nq * 16 + c][mk * 16 + gq * 4] = make_uint2(r0, r1);
            }
        }
        __builtin_amdgcn_sched_barrier(0);   // pin P-stores before pf ds_reads
        // PV
        bf16x8 pf[4], vf[2];
        #pragma unroll
        for (int mt = 0; mt < 4; mt++)
            pf[mt] = *(const bf16x8*)&Pb[wave][mt * 16 + c][gq * 8];
        #pragma unroll
        for (int nv = 0; nv < 2; nv++)
            vf[nv] = *(const bf16x8*)&VT[lh][nv * 16 + c][s * 32 + gq * 8];
        #pragma unroll
        for (int mt = 0; mt < 4; mt++)
            #pragma unroll
            for (int nv = 0; nv < 2; nv++)
                acc[mt][nv] = __builtin_amdgcn_mfma_f32_16x16x32_bf16(pf[mt], vf[nv], acc[mt][nv], 0, 0, 0);
    }

    #pragma unroll
    for (int nq = 0; nq < 4; nq++) {
        lsum[nq] += __shfl_xor(lsum[nq], 16, 64);
        lsum[nq] += __shfl_xor(lsum[nq], 32, 64);
    }

    // global (IRCA means) step: 8 keys (+8 dup rows masked), P pre-weighted by l_local/l_global
    {
        #pragma unroll
        for (int nq = 0; nq < 4; nq++) {
            f32x4 sg = __builtin_amdgcn_mfma_f32_16x16x32_bf16(kgf, qf[nq],
                    (f32x4){0.f, 0.f, 0.f, 0.f}, 0, 0, 0);
            float p0, p1, p2, p3;
            if (gq < 2) {
                p0 = exp2f(sg[0]); p1 = exp2f(sg[1]);
                p2 = exp2f(sg[2]); p3 = exp2f(sg[3]);
            } else { p0 = p1 = p2 = p3 = 0.f; }
            float lg = (p0 + p1) + (p2 + p3);
            lg += __shfl_xor(lg, 16, 64);
            lg += __shfl_xor(lg, 32, 64);
            float w = lsum[nq] / lg;
            p0 *= w; p1 *= w; p2 *= w; p3 *= w;
            u32 r0, r1;
            asm("v_cvt_pk_bf16_f32 %0, %1, %2" : "=v"(r0) : "v"(p0), "v"(p1));
            asm("v_cvt_pk_bf16_f32 %0, %1, %2" : "=v"(r1) : "v"(p2), "v"(p3));
            *(uint2*)&Pb[wave][nq * 16 + c][gq * 4] = make_uint2(r0, r1);
        }
        __builtin_amdgcn_sched_barrier(0);   // pin P-stores before pf ds_reads
        bf16x8 zf;
        #pragma unroll
        for (int z8 = 0; z8 < 8; z8++) zf[z8] = 0;
        bf16x8 pf[4], vf[2];
        #pragma unroll
        for (int mt = 0; mt < 4; mt++)
            pf[mt] = *(const bf16x8*)&Pb[wave][mt * 16 + c][gq * 8];
        #pragma unroll
        for (int nv = 0; nv < 2; nv++)
            vf[nv] = (gq == 0) ? *(const bf16x8*)&VT[lh][nv * 16 + c][256] : zf;
        #pragma unroll
        for (int mt = 0; mt < 4; mt++)
            #pragma unroll
            for (int nv = 0; nv < 2; nv++)
                acc[mt][nv] = __builtin_amdgcn_mfma_f32_16x16x32_bf16(pf[mt], vf[nv], acc[mt][nv], 0, 0, 0);
    }

    // broadcast l via (dead) Pb region, then normalize into registers
    float* lf = (float*)&Pb[wave][0][0];
    if (gq == 0) {
        #pragma unroll
        for (int nq = 0; nq < 4; nq++) lf[nq * 16 + c] = lsum[nq];
    }
    __builtin_amdgcn_sched_barrier(0);       // pin lf stores before lf reads
    u16 ov[4][2][4];
    #pragma unroll
    for (int mt = 0; mt < 4; mt++) {
        float il[4];
        #pragma unroll
        for (int r = 0; r < 4; r++)
            il[r] = 1.f / lf[mt * 16 + gq * 4 + r];
        #pragma unroll
        for (int nv = 0; nv < 2; nv++)
            #pragma unroll
            for (int r = 0; r < 4; r++)
                ov[mt][nv][r] = f2b(acc[mt][nv][r] * il[r]);
    }

    // stage out-tile [128 rows][64 ch] into LDS (reuse VT; pad 68 -> 2 lanes/bank, free)
    __syncthreads();                         // all waves done reading VT/Pb
    u16* st = (u16*)&VT[0][0][0];            // [128][68]
    #pragma unroll
    for (int mt = 0; mt < 4; mt++)
        #pragma unroll
        for (int nv = 0; nv < 2; nv++)
            #pragma unroll
            for (int r = 0; r < 4; r++)
                st[(qh * 64 + mt * 16 + gq * 4 + r) * 68 + lh * 32 + nv * 16 + c] = ov[mt][nv][r];
    __syncthreads();
    // cooperative stores: 8 consecutive lanes cover one FULL 128 B line per instr
    {
        const int rl0 = t >> 3;              // 0..31
        const int seg = t & 7;
        #pragma unroll
        for (int p = 0; p < 4; p++) {
            int rl = rl0 + p * 32;
            uint4 v4 = *(const uint4*)&st[rl * 68 + seg * 8];
            *(uint4*)&outp[(brow + g * GSZ + rl) * 128 + hp * 64 + seg * 8] = v4;
        }
    }
}

// ---------------- depthwise 5x5 conv + bias + gelu + h1-add, vectorized ----------------
__global__ __launch_bounds__(256) void k_dw(const u16* __restrict__ himg,
        const float* __restrict__ dww, const float* __restrict__ dwb, u16* __restrict__ dsum) {
    const int mc = blockIdx.y, b = blockIdx.z;
    const int t = threadIdx.x;
    const int y = blockIdx.x * 32 + (t >> 4) * 2;   // output rows y, y+1
    const int xb = (t & 15) * 8;
    float wgt[25];
    #pragma unroll
    for (int i = 0; i < 25; i++) wgt[i] = dww[mc * 25 + i];
    const float bsv = dwb[mc];
    const u16* src = himg + ((size_t)b * MLPD + mc) * NTOK;
    u16* dst = dsum + ((size_t)b * MLPD + mc) * NTOK;

    float w[6][12];   // rows y-2..y+3, cols xb-2..xb+9 (fully static indexing)
    #pragma unroll
    for (int r = 0; r < 6; r++) {
        int ysrc = y - 2 + r;
        bool vy = (ysrc >= 0 && ysrc < HH);
        const u16* rp = src + ysrc * WW + xb;
        uint4 aq = vy ? *(const uint4*)(rp - 8) : make_uint4(0u, 0u, 0u, 0u);
        uint4 bq = vy ? *(const uint4*)(rp)     : make_uint4(0u, 0u, 0u, 0u);
        uint4 cq = vy ? *(const uint4*)(rp + 8) : make_uint4(0u, 0u, 0u, 0u);
        w[r][0]  = ulo(aq.w); w[r][1]  = uhi(aq.w);
        w[r][2]  = ulo(bq.x); w[r][3]  = uhi(bq.x);
        w[r][4]  = ulo(bq.y); w[r][5]  = uhi(bq.y);
        w[r][6]  = ulo(bq.z); w[r][7]  = uhi(bq.z);
        w[r][8]  = ulo(bq.w); w[r][9]  = uhi(bq.w);
        w[r][10] = ulo(cq.x); w[r][11] = uhi(cq.x);
        if (xb == 0)   { w[r][0]  = 0.f; w[r][1]  = 0.f; }
        if (xb == 120) { w[r][10] = 0.f; w[r][11] = 0.f; }
    }

    float acc0[8], acc1[8];
    #pragma unroll
    for (int px = 0; px < 8; px++) { acc0[px] = 0.f; acc1[px] = 0.f; }
    #pragma unroll
    for (int dy = 0; dy < 5; dy++)
        #pragma unroll
        for (int dx = 0; dx < 5; dx++) {
            float wv = wgt[dy * 5 + dx];
            #pragma unroll
            for (int px = 0; px < 8; px++) {
                acc0[px] = fmaf(wv, w[dy][px + dx], acc0[px]);
                acc1[px] = fmaf(wv, w[dy + 1][px + dx], acc1[px]);
            }
        }

    u32 o0[4], o1[4];
    #pragma unroll
    for (int px = 0; px < 8; px += 2) {
        u16 a0 = f2b(w[2][px + 2] + gelu_f(acc0[px] + bsv));
        u16 a1 = f2b(w[2][px + 3] + gelu_f(acc0[px + 1] + bsv));
        o0[px >> 1] = (u32)a0 | ((u32)a1 << 16);
        u16 b0 = f2b(w[3][px + 2] + gelu_f(acc1[px] + bsv));
        u16 b1 = f2b(w[3][px + 3] + gelu_f(acc1[px + 1] + bsv));
        o1[px >> 1] = (u32)b0 | ((u32)b1 << 16);
    }
    *(uint4*)(dst + y * WW + xb) = *(uint4*)o0;
    *(uint4*)(dst + (y + 1) * WW + xb) = *(uint4*)o1;
}

extern "C" void kernel_launch(void* const* d_in, const int* in_sizes, int n_in,
                              void* d_out, int out_size, void* d_ws, size_t ws_size,
                              hipStream_t stream) {
    const float* x       = (const float*)d_in[0];
    const float* means   = (const float*)d_in[1];
    const float* ln1_w   = (const float*)d_in[2];
    const float* ln1_b   = (const float*)d_in[3];
    const float* wq      = (const float*)d_in[4];
    const float* wk      = (const float*)d_in[5];
    const float* wv      = (const float*)d_in[6];
    const float* wproj   = (const float*)d_in[7];
    const float* irca_wk = (const float*)d_in[8];
    const float* irca_wv = (const float*)d_in[9];
    const float* conv1w  = (const float*)d_in[10];
    const float* ln2_w   = (const float*)d_in[11];
    const float* ln2_b   = (const float*)d_in[12];
    const float* fc1_w   = (const float*)d_in[13];
    const float* fc1_b   = (const float*)d_in[14];
    const float* dw_w    = (const float*)d_in[15];
    const float* dw_b    = (const float*)d_in[16];
    const float* fc2_w   = (const float*)d_in[17];
    const float* fc2_b   = (const float*)d_in[18];
    float* out = (float*)d_out;

    const size_t need = 202514432;
    if (ws_size < need) return;

    char* base = (char*)d_ws;
    float* mhat  = (float*)(base);                 // 4096 B
    u16*   kgbb  = (u16*)(base + 4096);            // 2048 B
    u16*   vgtb  = (u16*)(base + 6144);            // 2048 B
    int*   bucket = (int*)(base + 8192);           // 524288 B (weights+iinv overlay after sort)
    u16*   wqkv  = (u16*)(base + 8192);            // 98304 B (wq|wk|wv stacked)
    u16*   wfub  = wqkv + 3 * 16384;               // 32768 B
    u16*   fc1b  = wfub + 16384;                   // 65536 B
    u16*   fc2b  = fc1b + 32768;                   // 65536 B
    u16*   iinv  = (u16*)(base + 270336);          // 262144 B (hole after fc2b, inside dead bucket)
    int*   cnt   = (int*)(base + 532480);
    int*   cbase = (int*)(base + 598016);
    int*   gidx  = (int*)(base + 663552);
    u16*   Abase = (u16*)(base + 1187840);         // 100663296 B
    u16*   x2b   = (u16*)(base + 101851136);       // 33554432 B
    u16*   dsum  = (u16*)(base + 135405568);       // 67108864 B

    u16* qkb  = Abase;                 // [B][NTOK][256] (q|k)
    u16* vimg = Abase + 2 * BIG;       // [B][128][NTOK] image-layout V
    u16* himg = Abase;                 // [B][256][NTOK] (after qk dead)
    u16* xmb  = Abase + 2 * BIG;       // [B][NTOK][128] (after vimg dead)
    u16* xnb   = (u16*)d_out;          // LN1 out (d_out scratch)
    u16* attnb = (u16*)d_out;          // attention out, SORTED order (overwrites xnb)

    k_prep<<<NTm, 128, 0, stream>>>(means, irca_wk, irca_wv, mhat, kgbb, vgtb);
    k_ln1<<<BB * NTOK / 64, 256, 0, stream>>>(x, ln1_w, ln1_b, mhat, xnb, bucket);
    k_count<<<BB * NTOK / 64, 64, 0, stream>>>(bucket, cnt);
    k_scan<<<BB, 64, 0, stream>>>(cnt, cbase);
    k_place<<<BB * NTOK / 64, 64, 0, stream>>>(bucket, cbase, gidx);
    k_inv<<<BB * NTOK / 256, 256, 0, stream>>>(gidx, iinv);

    // weight conversions (bucket region is dead now)
    k_cvtall<<<448, 256, 0, stream>>>(wq, wk, wv, fc1_w, fc2_w, wqkv, fc1b, fc2b);
    k_fuse<<<64, 256, 0, stream>>>(conv1w, wproj, wfub);

    // q prescale now includes log2(e) so attn softmax uses raw v_exp (exp2f)
    const float qsc2 = 0.25503489924160945f;  // (1/sqrt(32)) * log2(e)
    // gathered QK: [B][NTOK][256] token layout
    g_mfma<128, 256, 1, 0, 0, 0, 0, 0, 1, 0><<<dim3(128, 2, BB), 256, 0, stream>>>(
        xnb, wqkv, nullptr, nullptr, gidx, qkb, qsc2, nullptr, nullptr, nullptr);
    // gathered V: [B][128][NTOK] image layout (free transpose for attn staging)
    g_mfma<128, 128, 1, 0, 0, 0, 0, 1, 1, 0><<<dim3(128, 1, BB), 256, 0, stream>>>(
        xnb, wqkv + 2 * 16384, nullptr, nullptr, gidx, vimg, 1.0f, nullptr, nullptr, nullptr);

    k_attn<<<dim3(NGRP, 2, BB), 256, 0, stream>>>(qkb, vimg, kgbb, vgtb, attnb);

    // x2 = x_img + gather(attn_sorted, iinv) @ Wfused^T, fused LN2:
    // writes x2b AND xmb (bf16 token)
    g_mfma<128, 128, 2, 0, 0, 0, 1, 0, 1, 1><<<dim3(128, 1, BB), 256, 0, stream>>>(
        attnb, wfub, nullptr, x, (const int*)iinv, x2b, 1.0f, ln2_w, ln2_b, xmb);

    g_mfma<128, 256, 0, 0, 1, 1, 0, 1, 1, 0><<<dim3(128, 2, BB), 256, 0, stream>>>(
        xmb, fc1b, fc1_b, nullptr, nullptr, himg, 1.0f, nullptr, nullptr, nullptr);
    k_dw<<<dim3(4, MLPD, BB), 256, 0, stream>>>(himg, dw_w, dw_b, dsum);
    // fc2 from image-layout dsum, + bf16 token resid x2, fp32 image out
    g_mfma<256, 128, 0, 1, 1, 0, 3, 1, 0, 0><<<dim3(128, 1, BB), 256, 0, stream>>>(
        dsum, fc2b, fc2_b, x2b, nullptr, out, 1.0f, nullptr, nullptr, nullptr);

    (void)in_sizes; (void)n_in; (void)out_size;
}

// Round 8
// 319.877 us; speedup vs baseline: 1.0686x; 1.0686x over previous
//
#include <hip/hip_runtime.h>
#include <math.h>

typedef unsigned short u16;
typedef unsigned int u32;
typedef __attribute__((ext_vector_type(8))) short bf16x8;
typedef __attribute__((ext_vector_type(4))) float f32x4;

constexpr int BB   = 8;
constexpr int DIMC = 128;
constexpr int HH   = 128;
constexpr int WW   = 128;
constexpr int NTOK = HH * WW;       // 16384
constexpr int QKD  = 128;
constexpr int MLPD = 256;
constexpr int NTm  = 8;
constexpr int GSZ  = 128;
constexpr int NGRP = NTOK / GSZ;    // 128
constexpr size_t BIG = 16777216;    // 8*16384*128 elements

__device__ __forceinline__ float gelu_f(float v) {
    return 0.5f * v * (1.0f + erff(v * 0.70710678118654752440f));
}
__device__ __forceinline__ float b2f(u16 u) {
    return __uint_as_float(((u32)u) << 16);
}
__device__ __forceinline__ u16 f2b(float f) {
    u32 x = __float_as_uint(f);
    return (u16)((x + 0x7fffu + ((x >> 16) & 1u)) >> 16);
}
__device__ __forceinline__ float ulo(u32 u) { return __uint_as_float(u << 16); }
__device__ __forceinline__ float uhi(u32 u) { return __uint_as_float(u & 0xffff0000u); }
// raw v_exp_f32 (2^x) via the compiler-known intrinsic: correct trans-op
// hazard handling (round-7's bare inline asm omitted the required wait
// state -> NaN), and none of libm exp2f's OCML fixup code.
__device__ __forceinline__ float exp2_raw(float x) {
    return __builtin_amdgcn_exp2f(x);
}

// ---------------- prep: normalized means (fp32), global K (bf16), global V^T (bf16) ----------------
__global__ __launch_bounds__(128) void k_prep(const float* __restrict__ means,
        const float* __restrict__ iwk, const float* __restrict__ iwv,
        float* __restrict__ mhat, u16* __restrict__ kgbb, u16* __restrict__ vgtb) {
    __shared__ float sm[DIMC];
    __shared__ float inv_s;
    int tt = blockIdx.x;          // mean row 0..7
    int t = threadIdx.x;          // 0..127
    sm[t] = means[tt * DIMC + t];
    __syncthreads();
    if (t == 0) {
        float s = 0.f;
        for (int c = 0; c < DIMC; c++) s += sm[c] * sm[c];
        inv_s = 1.f / fmaxf(sqrtf(s), 1e-12f);
    }
    __syncthreads();
    mhat[tt * DIMC + t] = sm[t] * inv_s;
    float sk = 0.f, sv = 0.f;
    #pragma unroll 8
    for (int c = 0; c < DIMC; c++) {
        sk = fmaf(sm[c], iwk[t * DIMC + c], sk);
        sv = fmaf(sm[c], iwv[t * DIMC + c], sv);
    }
    kgbb[tt * DIMC + t] = f2b(sk);
    vgtb[(t >> 5) * 256 + (t & 31) * 8 + tt] = f2b(sv);   // [head][dv][8]
}

// ---------------- all weight converts fp32->bf16 in one launch ----------------
__global__ __launch_bounds__(256) void k_cvtall(const float* __restrict__ wq,
        const float* __restrict__ wk, const float* __restrict__ wv,
        const float* __restrict__ fc1, const float* __restrict__ fc2,
        u16* __restrict__ wqkv, u16* __restrict__ fc1b, u16* __restrict__ fc2b) {
    int i = blockIdx.x * 256 + threadIdx.x;
    if (i < 49152) {
        const float* s = (i < 16384) ? wq : (i < 32768 ? wk : wv);
        wqkv[i] = f2b(s[i & 16383]);
    } else if (i < 81920) {
        fc1b[i - 49152] = f2b(fc1[i - 49152]);
    } else if (i < 114688) {
        fc2b[i - 81920] = f2b(fc2[i - 81920]);
    }
}

// ---------------- fused conv1x1 @ wproj ----------------
__global__ __launch_bounds__(256) void k_fuse(const float* __restrict__ c1,
        const float* __restrict__ wp, u16* __restrict__ wf) {
    __shared__ float wpS[DIMC * DIMC];
    int t = threadIdx.x;
    for (int i = t; i < DIMC * DIMC; i += 256) wpS[i] = wp[i];
    __syncthreads();
    int o = blockIdx.x * 2 + (t >> 7);
    int c = t & 127;
    float s = 0.f;
    #pragma unroll 8
    for (int m = 0; m < DIMC; m++) s = fmaf(c1[o * DIMC + m], wpS[m * DIMC + c], s);
    wf[o * DIMC + c] = f2b(s);
}

// ---------------- LN1 + cluster scores + bucket (bf16 xn out), channel-split ----------------
__global__ __launch_bounds__(256) void k_ln1(const float* __restrict__ x,
        const float* __restrict__ lw, const float* __restrict__ lb,
        const float* __restrict__ mhat, u16* __restrict__ xn, int* __restrict__ bucket) {
    __shared__ float smh[NTm * DIMC];     // 4 KB
    __shared__ float lwb[DIMC], lbb[DIMC];
    __shared__ float red[4][64][3];       // sum, sq (+pad -> 2-way max)
    __shared__ float scr[4][64][9];       // partial scores (+pad -> 2-way max)
    const int chunk = blockIdx.x;         // 0..2047
    const int b = chunk >> 8;
    const int n0 = (chunk & 255) << 6;
    const int t = threadIdx.x;
    const int cg = t >> 6, tok = t & 63;
    const int n = n0 + tok;
    const int cbase = cg * 32;
    for (int i = t; i < NTm * DIMC; i += 256) smh[i] = mhat[i];
    if (t < DIMC) { lwb[t] = lw[t]; lbb[t] = lb[t]; }

    const float* xb = x + (size_t)b * DIMC * NTOK + (size_t)cbase * NTOK + n;
    float xv[32];
    float sum = 0.f, sq = 0.f;
    #pragma unroll
    for (int c = 0; c < 32; c++) {
        float v = xb[(size_t)c * NTOK];
        xv[c] = v;
        sum += v; sq += v * v;
    }
    red[cg][tok][0] = sum;
    red[cg][tok][1] = sq;
    __syncthreads();                      // covers smh/lwb staging + red
    float s0 = red[0][tok][0] + red[1][tok][0] + red[2][tok][0] + red[3][tok][0];
    float q0 = red[0][tok][1] + red[1][tok][1] + red[2][tok][1] + red[3][tok][1];
    float mean = s0 * (1.0f / DIMC);
    float var = q0 * (1.0f / DIMC) - mean * mean;
    float rstd = rsqrtf(var + 1e-5f);

    float sc[NTm];
    #pragma unroll
    for (int j = 0; j < NTm; j++) sc[j] = 0.f;
    u32 opk[16];
    #pragma unroll
    for (int c = 0; c < 32; c += 2) {
        float v0 = (xv[c]     - mean) * rstd * lwb[cbase + c]     + lbb[cbase + c];
        float v1 = (xv[c + 1] - mean) * rstd * lwb[cbase + c + 1] + lbb[cbase + c + 1];
        #pragma unroll
        for (int j = 0; j < NTm; j++) {
            sc[j] = fmaf(v0, smh[j * DIMC + cbase + c], sc[j]);
            sc[j] = fmaf(v1, smh[j * DIMC + cbase + c + 1], sc[j]);
        }
        opk[c >> 1] = (u32)f2b(v0) | ((u32)f2b(v1) << 16);
    }
    u16* xnr = xn + ((size_t)b * NTOK + n) * DIMC + cbase;
    *(uint4*)(xnr + 0)  = make_uint4(opk[0],  opk[1],  opk[2],  opk[3]);
    *(uint4*)(xnr + 8)  = make_uint4(opk[4],  opk[5],  opk[6],  opk[7]);
    *(uint4*)(xnr + 16) = make_uint4(opk[8],  opk[9],  opk[10], opk[11]);
    *(uint4*)(xnr + 24) = make_uint4(opk[12], opk[13], opk[14], opk[15]);

    #pragma unroll
    for (int j = 0; j < NTm; j++) scr[cg][tok][j] = sc[j];
    __syncthreads();
    if (cg == 0) {
        float v0 = ((scr[0][tok][0] + scr[1][tok][0]) + (scr[2][tok][0] + scr[3][tok][0]));
        int best = 0; float bv = v0;
        #pragma unroll
        for (int j = 1; j < NTm; j++) {
            float v = ((scr[0][tok][j] + scr[1][tok][j]) + (scr[2][tok][j] + scr[3][tok][j]));
            if (v > bv) { bv = v; best = j; }
        }
        bucket[b * NTOK + n] = best;
    }
}

// ---------------- stable counting sort ----------------
__global__ __launch_bounds__(64) void k_count(const int* __restrict__ bucket, int* __restrict__ cnt) {
    int chunk = blockIdx.x;
    int bk = bucket[(chunk << 6) + threadIdx.x];
    #pragma unroll
    for (int j = 0; j < NTm; j++) {
        unsigned long long m = __ballot(bk == j);
        if (threadIdx.x == 0) cnt[chunk * NTm + j] = (int)__popcll(m);
    }
}

__global__ __launch_bounds__(64) void k_scan(const int* __restrict__ cnt, int* __restrict__ base) {
    __shared__ int sc[256 * NTm];
    __shared__ int bb[NTm], tot[NTm];
    int b = blockIdx.x, t = threadIdx.x;
    for (int i = t; i < 256 * NTm; i += 64) sc[i] = cnt[b * 256 * NTm + i];
    __syncthreads();
    if (t < NTm) {
        int run = 0;
        for (int c = 0; c < 256; c++) {
            int v = sc[c * NTm + t];
            sc[c * NTm + t] = run;
            run += v;
        }
        tot[t] = run;
    }
    __syncthreads();
    if (t == 0) {
        int a = 0;
        for (int j = 0; j < NTm; j++) { bb[j] = a; a += tot[j]; }
    }
    __syncthreads();
    for (int i = t; i < 256 * NTm; i += 64) base[b * 256 * NTm + i] = sc[i] + bb[i & 7];
}

__global__ __launch_bounds__(64) void k_place(const int* __restrict__ bucket,
        const int* __restrict__ base, int* __restrict__ gidx) {
    int chunk = blockIdx.x;
    int lane = threadIdx.x;
    int nf = (chunk << 6) + lane;
    int bk = bucket[nf];
    unsigned long long lower = (1ull << lane) - 1ull;
    int rank = 0;
    #pragma unroll
    for (int j = 0; j < NTm; j++) {
        unsigned long long m = __ballot(bk == j);
        if (bk == j) rank = (int)__popcll(m & lower);
    }
    int b = nf >> 14;
    int pos = base[chunk * NTm + bk] + rank;
    gidx[b * NTOK + pos] = nf & (NTOK - 1);
}

// ---------------- invert permutation: iinv[token] = sorted position (u16) ----------------
__global__ __launch_bounds__(256) void k_inv(const int* __restrict__ gidx, u16* __restrict__ iinv) {
    int i = blockIdx.x * 256 + threadIdx.x;   // 0 .. B*NTOK-1
    int b = i >> 14;
    iinv[((size_t)b << 14) + gidx[i]] = (u16)(i & (NTOK - 1));
}

// ---------------- MFMA bf16 GEMM: C[m][n] = sum_k A[m][k]*W[n][k] ----------------
// AIMG: A is bf16 image-layout [B][KDIM][NTOK] (stage with transpose)
// GATHER: 0 none, 1 int32 index (gidx), 2 u16 index (iinv)
// RES: 0 none, 1 fp32 image resid, 3 bf16 token resid
// STIMG: 1 = image-layout store; CBF: 1 = bf16 store, 0 = fp32
// LN2F: fused LayerNorm epilogue (requires NOUT=128, RES=1, grid.y=1)
// ascale multiplies acc when blockIdx.y==0 (used to pre-scale q)
template<int KDIM, int NOUT, int GATHER, int AIMG, int BIASF, int GELUF, int RES, int STIMG, int CBF, int LN2F>
__global__ __launch_bounds__(256) void g_mfma(const u16* __restrict__ A, const u16* __restrict__ W,
        const float* __restrict__ bias, const void* __restrict__ resid,
        const int* __restrict__ gidx, void* __restrict__ Cout, float ascale,
        const float* __restrict__ lnw, const float* __restrict__ lnb, void* __restrict__ Cout2) {
    __shared__ u16 As[128 * 40];
    __shared__ u16 Ws[128 * 40];
    const int b = blockIdx.z;
    const int m0 = blockIdx.x * 128;
    const int n0 = blockIdx.y * 128;
    const int t = threadIdx.x;
    const int lane = t & 63;
    const int wave = t >> 6;
    const int wm = (wave & 1) * 64;
    const int wn = (wave >> 1) * 64;
    const int srow = t >> 2;
    const int sko = (t & 3) * 8;
    const u16* pA0 = nullptr; const u16* pA1 = nullptr;
    if (!AIMG) {
        int ra0 = m0 + srow, ra1 = m0 + 64 + srow;
        if (GATHER == 1) {
            ra0 = gidx[b * NTOK + ra0];
            ra1 = gidx[b * NTOK + ra1];
        } else if (GATHER == 2) {
            const u16* gi = (const u16*)gidx;
            ra0 = gi[b * NTOK + ra0];
            ra1 = gi[b * NTOK + ra1];
        }
        pA0 = A + ((size_t)b * NTOK + ra0) * KDIM + sko;
        pA1 = A + ((size_t)b * NTOK + ra1) * KDIM + sko;
    }
    const u16* pW0 = W + (size_t)(n0 + srow) * KDIM + sko;
    const u16* pW1 = W + (size_t)(n0 + 64 + srow) * KDIM + sko;

    f32x4 acc[4][4];
    #pragma unroll
    for (int i = 0; i < 4; i++)
        #pragma unroll
        for (int j = 0; j < 4; j++) acc[i][j] = (f32x4){0.f, 0.f, 0.f, 0.f};

    for (int k0 = 0; k0 < KDIM; k0 += 32) {
        uint4 a0, a1, w0, w1;
        u16 e[16];
        if (!AIMG) {
            a0 = *(const uint4*)(pA0 + k0);
            a1 = *(const uint4*)(pA1 + k0);
        } else {
            const int kk2 = t & 31;
            const int tg = t >> 5;
            const u16* src = A + ((size_t)b * KDIM + k0 + kk2) * NTOK + m0 + tg * 16;
            *(uint4*)&e[0] = *(const uint4*)src;
            *(uint4*)&e[8] = *(const uint4*)(src + 8);
        }
        w0 = *(const uint4*)(pW0 + k0);
        w1 = *(const uint4*)(pW1 + k0);
        __syncthreads();
        if (!AIMG) {
            *(uint4*)&As[srow * 40 + sko] = a0;
            *(uint4*)&As[(64 + srow) * 40 + sko] = a1;
        } else {
            const int kk2 = t & 31;
            const int tg = t >> 5;
            #pragma unroll
            for (int j = 0; j < 16; j++) As[(tg * 16 + j) * 40 + kk2] = e[j];
        }
        *(uint4*)&Ws[srow * 40 + sko] = w0;
        *(uint4*)&Ws[(64 + srow) * 40 + sko] = w1;
        __syncthreads();
        bf16x8 af[4], bfv[4];
        #pragma unroll
        for (int i = 0; i < 4; i++)
            af[i] = *(bf16x8*)&As[(wm + i * 16 + (lane & 15)) * 40 + (lane >> 4) * 8];
        #pragma unroll
        for (int j = 0; j < 4; j++)
            bfv[j] = *(bf16x8*)&Ws[(wn + j * 16 + (lane & 15)) * 40 + (lane >> 4) * 8];
        #pragma unroll
        for (int i = 0; i < 4; i++)
            #pragma unroll
            for (int j = 0; j < 4; j++)
                acc[i][j] = __builtin_amdgcn_mfma_f32_16x16x32_bf16(af[i], bfv[j], acc[i][j], 0, 0, 0);
    }

    const int c2 = lane & 15, gq2 = lane >> 4;
    int colj[4];
    #pragma unroll
    for (int j = 0; j < 4; j++) colj[j] = n0 + wn + j * 16 + c2;

    if (LN2F) {
        #pragma unroll
        for (int i = 0; i < 4; i++) {
            int rbase = m0 + wm + i * 16 + gq2 * 4;
            #pragma unroll
            for (int j = 0; j < 4; j++) {
                const float* rf = (const float*)resid;
                float4 rr = *(const float4*)&rf[((size_t)b * NOUT + colj[j]) * NTOK + rbase];
                acc[i][j][0] += rr.x; acc[i][j][1] += rr.y;
                acc[i][j][2] += rr.z; acc[i][j][3] += rr.w;
            }
        }
        __syncthreads();                      // all waves done with As/Ws frag reads
        float* ps = (float*)&As[0];           // [2 halves][128 rows][2] = 2 KB, overlays As
        const int h = wn >> 6;
        float mean_[4][4], rstd_[4][4];
        #pragma unroll
        for (int i = 0; i < 4; i++)
            #pragma unroll
            for (int r = 0; r < 4; r++) {
                float s = 0.f, q = 0.f;
                #pragma unroll
                for (int j = 0; j < 4; j++) { float tv = acc[i][j][r]; s += tv; q += tv * tv; }
                s += __shfl_xor(s, 1, 64); q += __shfl_xor(q, 1, 64);
                s += __shfl_xor(s, 2, 64); q += __shfl_xor(q, 2, 64);
                s += __shfl_xor(s, 4, 64); q += __shfl_xor(q, 4, 64);
                s += __shfl_xor(s, 8, 64); q += __shfl_xor(q, 8, 64);
                if (c2 == 0) {
                    int rl = wm + i * 16 + gq2 * 4 + r;
                    ps[(h * 128 + rl) * 2 + 0] = s;
                    ps[(h * 128 + rl) * 2 + 1] = q;
                }
            }
        __syncthreads();
        #pragma unroll
        for (int i = 0; i < 4; i++)
            #pragma unroll
            for (int r = 0; r < 4; r++) {
                int rl = wm + i * 16 + gq2 * 4 + r;
                float s = ps[rl * 2 + 0] + ps[(128 + rl) * 2 + 0];
                float q = ps[rl * 2 + 1] + ps[(128 + rl) * 2 + 1];
                float mn = s * (1.0f / 128.0f);
                float vr = q * (1.0f / 128.0f) - mn * mn;
                mean_[i][r] = mn;
                rstd_[i][r] = rsqrtf(vr + 1e-5f);
            }
        float lwj[4], lbj[4];
        #pragma unroll
        for (int j = 0; j < 4; j++) { lwj[j] = lnw[colj[j]]; lbj[j] = lnb[colj[j]]; }
        u16* xo = (u16*)Cout;
        u16* mo = (u16*)Cout2;
        #pragma unroll
        for (int i = 0; i < 4; i++) {
            int rbase = m0 + wm + i * 16 + gq2 * 4;
            #pragma unroll
            for (int j = 0; j < 4; j++)
                #pragma unroll
                for (int r = 0; r < 4; r++) {
                    float tv = acc[i][j][r];
                    size_t off = ((size_t)b * NTOK + rbase + r) * NOUT + colj[j];
                    xo[off] = f2b(tv);
                    mo[off] = f2b((tv - mean_[i][r]) * rstd_[i][r] * lwj[j] + lbj[j]);
                }
        }
        return;
    }

    const float smul = (blockIdx.y == 0) ? ascale : 1.0f;
    float bj[4];
    #pragma unroll
    for (int j = 0; j < 4; j++) bj[j] = BIASF ? bias[colj[j]] : 0.f;
    #pragma unroll
    for (int i = 0; i < 4; i++) {
        int rbase = m0 + wm + i * 16 + gq2 * 4;
        #pragma unroll
        for (int j = 0; j < 4; j++) {
            f32x4 v = acc[i][j];
            v[0] *= smul; v[1] *= smul; v[2] *= smul; v[3] *= smul;
            if (BIASF) { v[0] += bj[j]; v[1] += bj[j]; v[2] += bj[j]; v[3] += bj[j]; }
            if (GELUF) { v[0] = gelu_f(v[0]); v[1] = gelu_f(v[1]); v[2] = gelu_f(v[2]); v[3] = gelu_f(v[3]); }
            if (RES == 1) {
                const float* rf = (const float*)resid;
                float4 rr = *(const float4*)&rf[((size_t)b * NOUT + colj[j]) * NTOK + rbase];
                v[0] += rr.x; v[1] += rr.y; v[2] += rr.z; v[3] += rr.w;
            } else if (RES == 3) {
                const u16* rb = (const u16*)resid;
                #pragma unroll
                for (int r = 0; r < 4; r++)
                    v[r] += b2f(rb[((size_t)b * NTOK + rbase + r) * NOUT + colj[j]]);
            }
            if (STIMG) {
                size_t off = ((size_t)b * NOUT + colj[j]) * NTOK + rbase;
                if (CBF) {
                    ushort4 o;
                    o.x = f2b(v[0]); o.y = f2b(v[1]); o.z = f2b(v[2]); o.w = f2b(v[3]);
                    *(ushort4*)((u16*)Cout + off) = o;
                } else {
                    *(float4*)((float*)Cout + off) = make_float4(v[0], v[1], v[2], v[3]);
                }
            } else {
                if (CBF) {
                    #pragma unroll
                    for (int r = 0; r < 4; r++)
                        ((u16*)Cout)[((size_t)b * NTOK + rbase + r) * NOUT + colj[j]] = f2b(v[r]);
                } else {
                    #pragma unroll
                    for (int r = 0; r < 4; r++)
                        ((float*)Cout)[((size_t)b * NTOK + rbase + r) * NOUT + colj[j]] = v[r];
                }
            }
        }
    }
}

// ---------------- MFMA windowed + global attention ----------------
// qkv: [B][NTOK][384] bf16 (q prescaled by log2e/sqrt(32)), sorted domain
// Softmax uses raw v_exp_f32 (2^x) via __builtin_amdgcn_exp2f.
// OUTPUT IS IN SORTED ORDER; epilogue stages the out-tile in LDS and does
// cooperative full-line (128 B) stores.
// ALL global loads (V-stage, Q, all 16 K-fragments, global-K) are issued
// before the staging barrier, so their HBM latency overlaps once.
// block = (group, head-pair, batch); 4 waves: wave = (qhalf<<1) | local-head
__global__ __launch_bounds__(256, 3) void k_attn(const u16* __restrict__ qkv,
        const u16* __restrict__ kgbb, const u16* __restrict__ vgtb,
        u16* __restrict__ outp) {
    __shared__ u16 VT[2][32][264];   // V^T per local head: [dv][key 0..255 local, 256..263 global]
    __shared__ u16 Pb[4][64][40];    // per-wave P buffer [q][key-chunk 32 + pad]
    const int g = blockIdx.x, hp = blockIdx.y, b = blockIdx.z;
    const int t = threadIdx.x;
    const int wave = t >> 6, lane = t & 63;
    const int c = lane & 15, gq = lane >> 4;
    const int lh = wave & 1, head = hp * 2 + lh, qh = wave >> 1;
    const size_t brow = (size_t)b * NTOK;
    const bool lastg = (g == NGRP - 1);

    {   // stage V^T (local window keys)
        int key = t;
        int pos = (!lastg || key < GSZ) ? g * GSZ + key : NTOK - 1 - (key - GSZ);
        const u16* vp = qkv + (brow + pos) * 384 + 256 + hp * 64;
        #pragma unroll
        for (int i = 0; i < 8; i++) {
            uint4 v = *(const uint4*)(vp + i * 8);
            u16 e[8];
            *(uint4*)e = v;
            #pragma unroll
            for (int j = 0; j < 8; j++) {
                int d = i * 8 + j;
                VT[d >> 5][d & 31][key] = e[j];
            }
        }
        if (t < 64) {   // global V^T -> keys 256..263
            int l2 = t >> 5, dv = t & 31;
            uint4 v = *(const uint4*)(vgtb + ((size_t)(hp * 2 + l2) * 32 + dv) * 8);
            *(uint4*)&VT[l2][dv][256] = v;
        }
    }

    // prefetch Q, ALL K fragments, and global-K before the barrier
    const int q0 = g * GSZ + qh * 64;
    bf16x8 qf[4];
    #pragma unroll
    for (int nq = 0; nq < 4; nq++)
        qf[nq] = *(const bf16x8*)(qkv + (brow + q0 + nq * 16 + c) * 384 + head * 32 + gq * 8);

    const u16* kbp = qkv + brow * 384 + 128 + head * 32 + gq * 8;
    bf16x8 kfa[8][2];
    #pragma unroll
    for (int s = 0; s < 8; s++)
        #pragma unroll
        for (int mk = 0; mk < 2; mk++) {
            int kl = s * 32 + mk * 16 + c;
            int pos = (!lastg || kl < GSZ) ? g * GSZ + kl : NTOK - 1 - (kl - GSZ);
            kfa[s][mk] = *(const bf16x8*)(kbp + (size_t)pos * 384);
        }
    bf16x8 kgf = *(const bf16x8*)(kgbb + (c & 7) * 128 + head * 32 + gq * 8);

    __syncthreads();

    f32x4 acc[4][2];
    #pragma unroll
    for (int i = 0; i < 4; i++)
        #pragma unroll
        for (int j = 0; j < 2; j++) acc[i][j] = (f32x4){0.f, 0.f, 0.f, 0.f};
    float lsum[4] = {0.f, 0.f, 0.f, 0.f};

    for (int s = 0; s < 8; s++) {
        // S^T = K x Q^T : lane holds 4 consecutive keys for q-col c
        #pragma unroll
        for (int mk = 0; mk < 2; mk++) {
            #pragma unroll
            for (int nq = 0; nq < 4; nq++) {
                f32x4 st = __builtin_amdgcn_mfma_f32_16x16x32_bf16(kfa[s][mk], qf[nq],
                        (f32x4){0.f, 0.f, 0.f, 0.f}, 0, 0, 0);
                float p0 = exp2_raw(st[0]), p1 = exp2_raw(st[1]);
                float p2 = exp2_raw(st[2]), p3 = exp2_raw(st[3]);
                lsum[nq] += (p0 + p1) + (p2 + p3);
                u32 r0, r1;
                asm("v_cvt_pk_bf16_f32 %0, %1, %2" : "=v"(r0) : "v"(p0), "v"(p1));
                asm("v_cvt_pk_bf16_f32 %0, %1, %2" : "=v"(r1) : "v"(p2), "v"(p3));
                *(uint2*)&Pb[wave][nq * 16 + c][mk * 16 + gq * 4] = make_uint2(r0, r1);
            }
        }
        __builtin_amdgcn_sched_barrier(0);   // pin P-stores before pf ds_reads
        // PV
        bf16x8 pf[4], vf[2];
        #pragma unroll
        for (int mt = 0; mt < 4; mt++)
            pf[mt] = *(const bf16x8*)&Pb[wave][mt * 16 + c][gq * 8];
        #pragma unroll
        for (int nv = 0; nv < 2; nv++)
            vf[nv] = *(const bf16x8*)&VT[lh][nv * 16 + c][s * 32 + gq * 8];
        #pragma unroll
        for (int mt = 0; mt < 4; mt++)
            #pragma unroll
            for (int nv = 0; nv < 2; nv++)
                acc[mt][nv] = __builtin_amdgcn_mfma_f32_16x16x32_bf16(pf[mt], vf[nv], acc[mt][nv], 0, 0, 0);
    }

    #pragma unroll
    for (int nq = 0; nq < 4; nq++) {
        lsum[nq] += __shfl_xor(lsum[nq], 16, 64);
        lsum[nq] += __shfl_xor(lsum[nq], 32, 64);
    }

    // global (IRCA means) step: 8 keys (+8 dup rows masked), P pre-weighted by l_local/l_global
    {
        #pragma unroll
        for (int nq = 0; nq < 4; nq++) {
            f32x4 sg = __builtin_amdgcn_mfma_f32_16x16x32_bf16(kgf, qf[nq],
                    (f32x4){0.f, 0.f, 0.f, 0.f}, 0, 0, 0);
            float p0, p1, p2, p3;
            if (gq < 2) {
                p0 = exp2_raw(sg[0]); p1 = exp2_raw(sg[1]);
                p2 = exp2_raw(sg[2]); p3 = exp2_raw(sg[3]);
            } else { p0 = p1 = p2 = p3 = 0.f; }
            float lg = (p0 + p1) + (p2 + p3);
            lg += __shfl_xor(lg, 16, 64);
            lg += __shfl_xor(lg, 32, 64);
            float w = lsum[nq] / lg;
            p0 *= w; p1 *= w; p2 *= w; p3 *= w;
            u32 r0, r1;
            asm("v_cvt_pk_bf16_f32 %0, %1, %2" : "=v"(r0) : "v"(p0), "v"(p1));
            asm("v_cvt_pk_bf16_f32 %0, %1, %2" : "=v"(r1) : "v"(p2), "v"(p3));
            *(uint2*)&Pb[wave][nq * 16 + c][gq * 4] = make_uint2(r0, r1);
        }
        __builtin_amdgcn_sched_barrier(0);   // pin P-stores before pf ds_reads
        bf16x8 zf;
        #pragma unroll
        for (int z8 = 0; z8 < 8; z8++) zf[z8] = 0;
        bf16x8 pf[4], vf[2];
        #pragma unroll
        for (int mt = 0; mt < 4; mt++)
            pf[mt] = *(const bf16x8*)&Pb[wave][mt * 16 + c][gq * 8];
        #pragma unroll
        for (int nv = 0; nv < 2; nv++)
            vf[nv] = (gq == 0) ? *(const bf16x8*)&VT[lh][nv * 16 + c][256] : zf;
        #pragma unroll
        for (int mt = 0; mt < 4; mt++)
            #pragma unroll
            for (int nv = 0; nv < 2; nv++)
                acc[mt][nv] = __builtin_amdgcn_mfma_f32_16x16x32_bf16(pf[mt], vf[nv], acc[mt][nv], 0, 0, 0);
    }

    // broadcast l via (dead) Pb region, then normalize into registers
    float* lf = (float*)&Pb[wave][0][0];
    if (gq == 0) {
        #pragma unroll
        for (int nq = 0; nq < 4; nq++) lf[nq * 16 + c] = lsum[nq];
    }
    __builtin_amdgcn_sched_barrier(0);       // pin lf stores before lf reads
    u16 ov[4][2][4];
    #pragma unroll
    for (int mt = 0; mt < 4; mt++) {
        float il[4];
        #pragma unroll
        for (int r = 0; r < 4; r++)
            il[r] = 1.f / lf[mt * 16 + gq * 4 + r];
        #pragma unroll
        for (int nv = 0; nv < 2; nv++)
            #pragma unroll
            for (int r = 0; r < 4; r++)
                ov[mt][nv][r] = f2b(acc[mt][nv][r] * il[r]);
    }

    // stage out-tile [128 rows][64 ch] into LDS (reuse VT; pad 68 -> 2 lanes/bank, free)
    __syncthreads();                         // all waves done reading VT/Pb
    u16* st = (u16*)&VT[0][0][0];            // [128][68]
    #pragma unroll
    for (int mt = 0; mt < 4; mt++)
        #pragma unroll
        for (int nv = 0; nv < 2; nv++)
            #pragma unroll
            for (int r = 0; r < 4; r++)
                st[(qh * 64 + mt * 16 + gq * 4 + r) * 68 + lh * 32 + nv * 16 + c] = ov[mt][nv][r];
    __syncthreads();
    // cooperative stores: 8 consecutive lanes cover one FULL 128 B line per instr
    {
        const int rl0 = t >> 3;              // 0..31
        const int seg = t & 7;
        #pragma unroll
        for (int p = 0; p < 4; p++) {
            int rl = rl0 + p * 32;
            uint4 v4 = *(const uint4*)&st[rl * 68 + seg * 8];
            *(uint4*)&outp[(brow + g * GSZ + rl) * 128 + hp * 64 + seg * 8] = v4;
        }
    }
}

// ---------------- depthwise 5x5 conv + bias + gelu + h1-add, vectorized ----------------
__global__ __launch_bounds__(256) void k_dw(const u16* __restrict__ himg,
        const float* __restrict__ dww, const float* __restrict__ dwb, u16* __restrict__ dsum) {
    const int mc = blockIdx.y, b = blockIdx.z;
    const int t = threadIdx.x;
    const int y = blockIdx.x * 32 + (t >> 4) * 2;   // output rows y, y+1
    const int xb = (t & 15) * 8;
    float wgt[25];
    #pragma unroll
    for (int i = 0; i < 25; i++) wgt[i] = dww[mc * 25 + i];
    const float bsv = dwb[mc];
    const u16* src = himg + ((size_t)b * MLPD + mc) * NTOK;
    u16* dst = dsum + ((size_t)b * MLPD + mc) * NTOK;

    float w[6][12];   // rows y-2..y+3, cols xb-2..xb+9 (fully static indexing)
    #pragma unroll
    for (int r = 0; r < 6; r++) {
        int ysrc = y - 2 + r;
        bool vy = (ysrc >= 0 && ysrc < HH);
        const u16* rp = src + ysrc * WW + xb;
        uint4 aq = vy ? *(const uint4*)(rp - 8) : make_uint4(0u, 0u, 0u, 0u);
        uint4 bq = vy ? *(const uint4*)(rp)     : make_uint4(0u, 0u, 0u, 0u);
        uint4 cq = vy ? *(const uint4*)(rp + 8) : make_uint4(0u, 0u, 0u, 0u);
        w[r][0]  = ulo(aq.w); w[r][1]  = uhi(aq.w);
        w[r][2]  = ulo(bq.x); w[r][3]  = uhi(bq.x);
        w[r][4]  = ulo(bq.y); w[r][5]  = uhi(bq.y);
        w[r][6]  = ulo(bq.z); w[r][7]  = uhi(bq.z);
        w[r][8]  = ulo(bq.w); w[r][9]  = uhi(bq.w);
        w[r][10] = ulo(cq.x); w[r][11] = uhi(cq.x);
        if (xb == 0)   { w[r][0]  = 0.f; w[r][1]  = 0.f; }
        if (xb == 120) { w[r][10] = 0.f; w[r][11] = 0.f; }
    }

    float acc0[8], acc1[8];
    #pragma unroll
    for (int px = 0; px < 8; px++) { acc0[px] = 0.f; acc1[px] = 0.f; }
    #pragma unroll
    for (int dy = 0; dy < 5; dy++)
        #pragma unroll
        for (int dx = 0; dx < 5; dx++) {
            float wv = wgt[dy * 5 + dx];
            #pragma unroll
            for (int px = 0; px < 8; px++) {
                acc0[px] = fmaf(wv, w[dy][px + dx], acc0[px]);
                acc1[px] = fmaf(wv, w[dy + 1][px + dx], acc1[px]);
            }
        }

    u32 o0[4], o1[4];
    #pragma unroll
    for (int px = 0; px < 8; px += 2) {
        u16 a0 = f2b(w[2][px + 2] + gelu_f(acc0[px] + bsv));
        u16 a1 = f2b(w[2][px + 3] + gelu_f(acc0[px + 1] + bsv));
        o0[px >> 1] = (u32)a0 | ((u32)a1 << 16);
        u16 b0 = f2b(w[3][px + 2] + gelu_f(acc1[px] + bsv));
        u16 b1 = f2b(w[3][px + 3] + gelu_f(acc1[px + 1] + bsv));
        o1[px >> 1] = (u32)b0 | ((u32)b1 << 16);
    }
    *(uint4*)(dst + y * WW + xb) = *(uint4*)o0;
    *(uint4*)(dst + (y + 1) * WW + xb) = *(uint4*)o1;
}

extern "C" void kernel_launch(void* const* d_in, const int* in_sizes, int n_in,
                              void* d_out, int out_size, void* d_ws, size_t ws_size,
                              hipStream_t stream) {
    const float* x       = (const float*)d_in[0];
    const float* means   = (const float*)d_in[1];
    const float* ln1_w   = (const float*)d_in[2];
    const float* ln1_b   = (const float*)d_in[3];
    const float* wq      = (const float*)d_in[4];
    const float* wk      = (const float*)d_in[5];
    const float* wv      = (const float*)d_in[6];
    const float* wproj   = (const float*)d_in[7];
    const float* irca_wk = (const float*)d_in[8];
    const float* irca_wv = (const float*)d_in[9];
    const float* conv1w  = (const float*)d_in[10];
    const float* ln2_w   = (const float*)d_in[11];
    const float* ln2_b   = (const float*)d_in[12];
    const float* fc1_w   = (const float*)d_in[13];
    const float* fc1_b   = (const float*)d_in[14];
    const float* dw_w    = (const float*)d_in[15];
    const float* dw_b    = (const float*)d_in[16];
    const float* fc2_w   = (const float*)d_in[17];
    const float* fc2_b   = (const float*)d_in[18];
    float* out = (float*)d_out;

    const size_t need = 202514432;
    if (ws_size < need) return;

    char* base = (char*)d_ws;
    float* mhat  = (float*)(base);                 // 4096 B
    u16*   kgbb  = (u16*)(base + 4096);            // 2048 B
    u16*   vgtb  = (u16*)(base + 6144);            // 2048 B
    int*   bucket = (int*)(base + 8192);           // 524288 B (weights+iinv overlay after sort)
    u16*   wqkv  = (u16*)(base + 8192);            // 98304 B (wq|wk|wv stacked)
    u16*   wfub  = wqkv + 3 * 16384;               // 32768 B
    u16*   fc1b  = wfub + 16384;                   // 65536 B
    u16*   fc2b  = fc1b + 32768;                   // 65536 B
    u16*   iinv  = (u16*)(base + 270336);          // 262144 B (hole after fc2b, inside dead bucket)
    int*   cnt   = (int*)(base + 532480);
    int*   cbase = (int*)(base + 598016);
    int*   gidx  = (int*)(base + 663552);
    u16*   Abase = (u16*)(base + 1187840);         // 100663296 B: qkv -> {himg, xmb}
    u16*   x2b   = (u16*)(base + 101851136);       // 33554432 B
    u16*   dsum  = (u16*)(base + 135405568);       // 67108864 B

    u16* qkv  = Abase;                 // [B][NTOK][384]
    u16* himg = Abase;                 // [B][256][NTOK] (after qkv dead)
    u16* xmb  = Abase + 2 * BIG;       // [B][NTOK][128]
    u16* xnb   = (u16*)d_out;          // LN1 out (d_out scratch)
    u16* attnb = (u16*)d_out;          // attention out, SORTED order (overwrites xnb)

    k_prep<<<NTm, 128, 0, stream>>>(means, irca_wk, irca_wv, mhat, kgbb, vgtb);
    k_ln1<<<BB * NTOK / 64, 256, 0, stream>>>(x, ln1_w, ln1_b, mhat, xnb, bucket);
    k_count<<<BB * NTOK / 64, 64, 0, stream>>>(bucket, cnt);
    k_scan<<<BB, 64, 0, stream>>>(cnt, cbase);
    k_place<<<BB * NTOK / 64, 64, 0, stream>>>(bucket, cbase, gidx);
    k_inv<<<BB * NTOK / 256, 256, 0, stream>>>(gidx, iinv);

    // weight conversions (bucket region is dead now)
    k_cvtall<<<448, 256, 0, stream>>>(wq, wk, wv, fc1_w, fc2_w, wqkv, fc1b, fc2b);
    k_fuse<<<64, 256, 0, stream>>>(conv1w, wproj, wfub);

    // q prescale includes log2(e): attn softmax uses raw v_exp_f32 (2^x)
    const float qsc2 = 0.25503489924160945f;  // (1/sqrt(32)) * log2(e)
    // fused gathered QKV: [B][NTOK][384]
    g_mfma<128, 384, 1, 0, 0, 0, 0, 0, 1, 0><<<dim3(128, 3, BB), 256, 0, stream>>>(
        xnb, wqkv, nullptr, nullptr, gidx, qkv, qsc2, nullptr, nullptr, nullptr);

    k_attn<<<dim3(NGRP, 2, BB), 256, 0, stream>>>(qkv, kgbb, vgtb, attnb);

    // x2 = x_img + gather(attn_sorted, iinv) @ Wfused^T, fused LN2:
    // writes x2b AND xmb (bf16 token)
    g_mfma<128, 128, 2, 0, 0, 0, 1, 0, 1, 1><<<dim3(128, 1, BB), 256, 0, stream>>>(
        attnb, wfub, nullptr, x, (const int*)iinv, x2b, 1.0f, ln2_w, ln2_b, xmb);

    g_mfma<128, 256, 0, 0, 1, 1, 0, 1, 1, 0><<<dim3(128, 2, BB), 256, 0, stream>>>(
        xmb, fc1b, fc1_b, nullptr, nullptr, himg, 1.0f, nullptr, nullptr, nullptr);
    k_dw<<<dim3(4, MLPD, BB), 256, 0, stream>>>(himg, dw_w, dw_b, dsum);
    // fc2 from image-layout dsum, + bf16 token resid x2, fp32 image out
    g_mfma<256, 128, 0, 1, 1, 0, 3, 1, 0, 0><<<dim3(128, 1, BB), 256, 0, stream>>>(
        dsum, fc2b, fc2_b, x2b, nullptr, out, 1.0f, nullptr, nullptr, nullptr);

    (void)in_sizes; (void)n_in; (void)out_size;
}

// Round 9
// 312.900 us; speedup vs baseline: 1.0925x; 1.0223x over previous
//
#include <hip/hip_runtime.h>
#include <math.h>

typedef unsigned short u16;
typedef unsigned int u32;
typedef __attribute__((ext_vector_type(8))) short bf16x8;
typedef __attribute__((ext_vector_type(4))) float f32x4;

constexpr int BB   = 8;
constexpr int DIMC = 128;
constexpr int HH   = 128;
constexpr int WW   = 128;
constexpr int NTOK = HH * WW;       // 16384
constexpr int QKD  = 128;
constexpr int MLPD = 256;
constexpr int NTm  = 8;
constexpr int GSZ  = 128;
constexpr int NGRP = NTOK / GSZ;    // 128
constexpr size_t BIG = 16777216;    // 8*16384*128 elements

__device__ __forceinline__ float gelu_f(float v) {
    return 0.5f * v * (1.0f + erff(v * 0.70710678118654752440f));
}
__device__ __forceinline__ float b2f(u16 u) {
    return __uint_as_float(((u32)u) << 16);
}
__device__ __forceinline__ u16 f2b(float f) {
    u32 x = __float_as_uint(f);
    return (u16)((x + 0x7fffu + ((x >> 16) & 1u)) >> 16);
}
__device__ __forceinline__ float ulo(u32 u) { return __uint_as_float(u << 16); }
__device__ __forceinline__ float uhi(u32 u) { return __uint_as_float(u & 0xffff0000u); }
// raw v_exp_f32 (2^x) via the compiler-known intrinsic: correct trans-op
// hazard handling; none of libm exp2f's OCML fixup code.
__device__ __forceinline__ float exp2_raw(float x) {
    return __builtin_amdgcn_exp2f(x);
}

// ---------------- prep: normalized means (fp32), global K (bf16), global V^T (bf16) ----------------
__global__ __launch_bounds__(128) void k_prep(const float* __restrict__ means,
        const float* __restrict__ iwk, const float* __restrict__ iwv,
        float* __restrict__ mhat, u16* __restrict__ kgbb, u16* __restrict__ vgtb) {
    __shared__ float sm[DIMC];
    __shared__ float inv_s;
    int tt = blockIdx.x;          // mean row 0..7
    int t = threadIdx.x;          // 0..127
    sm[t] = means[tt * DIMC + t];
    __syncthreads();
    if (t == 0) {
        float s = 0.f;
        for (int c = 0; c < DIMC; c++) s += sm[c] * sm[c];
        inv_s = 1.f / fmaxf(sqrtf(s), 1e-12f);
    }
    __syncthreads();
    mhat[tt * DIMC + t] = sm[t] * inv_s;
    float sk = 0.f, sv = 0.f;
    #pragma unroll 8
    for (int c = 0; c < DIMC; c++) {
        sk = fmaf(sm[c], iwk[t * DIMC + c], sk);
        sv = fmaf(sm[c], iwv[t * DIMC + c], sv);
    }
    kgbb[tt * DIMC + t] = f2b(sk);
    vgtb[(t >> 5) * 256 + (t & 31) * 8 + tt] = f2b(sv);   // [head][dv][8]
}

// ---------------- all weight converts fp32->bf16 in one launch ----------------
__global__ __launch_bounds__(256) void k_cvtall(const float* __restrict__ wq,
        const float* __restrict__ wk, const float* __restrict__ wv,
        const float* __restrict__ fc1, const float* __restrict__ fc2,
        u16* __restrict__ wqkv, u16* __restrict__ fc1b, u16* __restrict__ fc2b) {
    int i = blockIdx.x * 256 + threadIdx.x;
    if (i < 49152) {
        const float* s = (i < 16384) ? wq : (i < 32768 ? wk : wv);
        wqkv[i] = f2b(s[i & 16383]);
    } else if (i < 81920) {
        fc1b[i - 49152] = f2b(fc1[i - 49152]);
    } else if (i < 114688) {
        fc2b[i - 81920] = f2b(fc2[i - 81920]);
    }
}

// ---------------- fused conv1x1 @ wproj ----------------
__global__ __launch_bounds__(256) void k_fuse(const float* __restrict__ c1,
        const float* __restrict__ wp, u16* __restrict__ wf) {
    __shared__ float wpS[DIMC * DIMC];
    int t = threadIdx.x;
    for (int i = t; i < DIMC * DIMC; i += 256) wpS[i] = wp[i];
    __syncthreads();
    int o = blockIdx.x * 2 + (t >> 7);
    int c = t & 127;
    float s = 0.f;
    #pragma unroll 8
    for (int m = 0; m < DIMC; m++) s = fmaf(c1[o * DIMC + m], wpS[m * DIMC + c], s);
    wf[o * DIMC + c] = f2b(s);
}

// ---------------- LN1 + cluster scores + bucket (bf16 xn out), channel-split ----------------
__global__ __launch_bounds__(256) void k_ln1(const float* __restrict__ x,
        const float* __restrict__ lw, const float* __restrict__ lb,
        const float* __restrict__ mhat, u16* __restrict__ xn, int* __restrict__ bucket) {
    __shared__ float smh[NTm * DIMC];     // 4 KB
    __shared__ float lwb[DIMC], lbb[DIMC];
    __shared__ float red[4][64][3];       // sum, sq (+pad -> 2-way max)
    __shared__ float scr[4][64][9];       // partial scores (+pad -> 2-way max)
    const int chunk = blockIdx.x;         // 0..2047
    const int b = chunk >> 8;
    const int n0 = (chunk & 255) << 6;
    const int t = threadIdx.x;
    const int cg = t >> 6, tok = t & 63;
    const int n = n0 + tok;
    const int cbase = cg * 32;
    for (int i = t; i < NTm * DIMC; i += 256) smh[i] = mhat[i];
    if (t < DIMC) { lwb[t] = lw[t]; lbb[t] = lb[t]; }

    const float* xb = x + (size_t)b * DIMC * NTOK + (size_t)cbase * NTOK + n;
    float xv[32];
    float sum = 0.f, sq = 0.f;
    #pragma unroll
    for (int c = 0; c < 32; c++) {
        float v = xb[(size_t)c * NTOK];
        xv[c] = v;
        sum += v; sq += v * v;
    }
    red[cg][tok][0] = sum;
    red[cg][tok][1] = sq;
    __syncthreads();                      // covers smh/lwb staging + red
    float s0 = red[0][tok][0] + red[1][tok][0] + red[2][tok][0] + red[3][tok][0];
    float q0 = red[0][tok][1] + red[1][tok][1] + red[2][tok][1] + red[3][tok][1];
    float mean = s0 * (1.0f / DIMC);
    float var = q0 * (1.0f / DIMC) - mean * mean;
    float rstd = rsqrtf(var + 1e-5f);

    float sc[NTm];
    #pragma unroll
    for (int j = 0; j < NTm; j++) sc[j] = 0.f;
    u32 opk[16];
    #pragma unroll
    for (int c = 0; c < 32; c += 2) {
        float v0 = (xv[c]     - mean) * rstd * lwb[cbase + c]     + lbb[cbase + c];
        float v1 = (xv[c + 1] - mean) * rstd * lwb[cbase + c + 1] + lbb[cbase + c + 1];
        #pragma unroll
        for (int j = 0; j < NTm; j++) {
            sc[j] = fmaf(v0, smh[j * DIMC + cbase + c], sc[j]);
            sc[j] = fmaf(v1, smh[j * DIMC + cbase + c + 1], sc[j]);
        }
        opk[c >> 1] = (u32)f2b(v0) | ((u32)f2b(v1) << 16);
    }
    u16* xnr = xn + ((size_t)b * NTOK + n) * DIMC + cbase;
    *(uint4*)(xnr + 0)  = make_uint4(opk[0],  opk[1],  opk[2],  opk[3]);
    *(uint4*)(xnr + 8)  = make_uint4(opk[4],  opk[5],  opk[6],  opk[7]);
    *(uint4*)(xnr + 16) = make_uint4(opk[8],  opk[9],  opk[10], opk[11]);
    *(uint4*)(xnr + 24) = make_uint4(opk[12], opk[13], opk[14], opk[15]);

    #pragma unroll
    for (int j = 0; j < NTm; j++) scr[cg][tok][j] = sc[j];
    __syncthreads();
    if (cg == 0) {
        float v0 = ((scr[0][tok][0] + scr[1][tok][0]) + (scr[2][tok][0] + scr[3][tok][0]));
        int best = 0; float bv = v0;
        #pragma unroll
        for (int j = 1; j < NTm; j++) {
            float v = ((scr[0][tok][j] + scr[1][tok][j]) + (scr[2][tok][j] + scr[3][tok][j]));
            if (v > bv) { bv = v; best = j; }
        }
        bucket[b * NTOK + n] = best;
    }
}

// ---------------- stable counting sort ----------------
__global__ __launch_bounds__(64) void k_count(const int* __restrict__ bucket, int* __restrict__ cnt) {
    int chunk = blockIdx.x;
    int bk = bucket[(chunk << 6) + threadIdx.x];
    #pragma unroll
    for (int j = 0; j < NTm; j++) {
        unsigned long long m = __ballot(bk == j);
        if (threadIdx.x == 0) cnt[chunk * NTm + j] = (int)__popcll(m);
    }
}

__global__ __launch_bounds__(64) void k_scan(const int* __restrict__ cnt, int* __restrict__ base) {
    __shared__ int sc[256 * NTm];
    __shared__ int bb[NTm], tot[NTm];
    int b = blockIdx.x, t = threadIdx.x;
    for (int i = t; i < 256 * NTm; i += 64) sc[i] = cnt[b * 256 * NTm + i];
    __syncthreads();
    if (t < NTm) {
        int run = 0;
        for (int c = 0; c < 256; c++) {
            int v = sc[c * NTm + t];
            sc[c * NTm + t] = run;
            run += v;
        }
        tot[t] = run;
    }
    __syncthreads();
    if (t == 0) {
        int a = 0;
        for (int j = 0; j < NTm; j++) { bb[j] = a; a += tot[j]; }
    }
    __syncthreads();
    for (int i = t; i < 256 * NTm; i += 64) base[b * 256 * NTm + i] = sc[i] + bb[i & 7];
}

__global__ __launch_bounds__(64) void k_place(const int* __restrict__ bucket,
        const int* __restrict__ base, int* __restrict__ gidx) {
    int chunk = blockIdx.x;
    int lane = threadIdx.x;
    int nf = (chunk << 6) + lane;
    int bk = bucket[nf];
    unsigned long long lower = (1ull << lane) - 1ull;
    int rank = 0;
    #pragma unroll
    for (int j = 0; j < NTm; j++) {
        unsigned long long m = __ballot(bk == j);
        if (bk == j) rank = (int)__popcll(m & lower);
    }
    int b = nf >> 14;
    int pos = base[chunk * NTm + bk] + rank;
    gidx[b * NTOK + pos] = nf & (NTOK - 1);
}

// ---------------- invert permutation: iinv[token] = sorted position (u16) ----------------
__global__ __launch_bounds__(256) void k_inv(const int* __restrict__ gidx, u16* __restrict__ iinv) {
    int i = blockIdx.x * 256 + threadIdx.x;   // 0 .. B*NTOK-1
    int b = i >> 14;
    iinv[((size_t)b << 14) + gidx[i]] = (u16)(i & (NTOK - 1));
}

// ---------------- MFMA bf16 GEMM: C[m][n] = sum_k A[m][k]*W[n][k] ----------------
// AIMG: A is bf16 image-layout [B][KDIM][NTOK] (stage with transpose)
// GATHER: 0 none, 1 int32 index (gidx), 2 u16 index (iinv)
// RES: 0 none, 1 fp32 image resid, 3 bf16 token resid
// STIMG: 1 = image-layout store; CBF: 1 = bf16 store, 0 = fp32
// LN2F: fused LayerNorm epilogue (requires NOUT=128, RES=1, grid.y=1)
// ascale multiplies acc when blockIdx.y==0 (used to pre-scale q)
template<int KDIM, int NOUT, int GATHER, int AIMG, int BIASF, int GELUF, int RES, int STIMG, int CBF, int LN2F>
__global__ __launch_bounds__(256) void g_mfma(const u16* __restrict__ A, const u16* __restrict__ W,
        const float* __restrict__ bias, const void* __restrict__ resid,
        const int* __restrict__ gidx, void* __restrict__ Cout, float ascale,
        const float* __restrict__ lnw, const float* __restrict__ lnb, void* __restrict__ Cout2) {
    __shared__ u16 As[128 * 40];
    __shared__ u16 Ws[128 * 40];
    const int b = blockIdx.z;
    const int m0 = blockIdx.x * 128;
    const int n0 = blockIdx.y * 128;
    const int t = threadIdx.x;
    const int lane = t & 63;
    const int wave = t >> 6;
    const int wm = (wave & 1) * 64;
    const int wn = (wave >> 1) * 64;
    const int srow = t >> 2;
    const int sko = (t & 3) * 8;
    const u16* pA0 = nullptr; const u16* pA1 = nullptr;
    if (!AIMG) {
        int ra0 = m0 + srow, ra1 = m0 + 64 + srow;
        if (GATHER == 1) {
            ra0 = gidx[b * NTOK + ra0];
            ra1 = gidx[b * NTOK + ra1];
        } else if (GATHER == 2) {
            const u16* gi = (const u16*)gidx;
            ra0 = gi[b * NTOK + ra0];
            ra1 = gi[b * NTOK + ra1];
        }
        pA0 = A + ((size_t)b * NTOK + ra0) * KDIM + sko;
        pA1 = A + ((size_t)b * NTOK + ra1) * KDIM + sko;
    }
    const u16* pW0 = W + (size_t)(n0 + srow) * KDIM + sko;
    const u16* pW1 = W + (size_t)(n0 + 64 + srow) * KDIM + sko;

    f32x4 acc[4][4];
    #pragma unroll
    for (int i = 0; i < 4; i++)
        #pragma unroll
        for (int j = 0; j < 4; j++) acc[i][j] = (f32x4){0.f, 0.f, 0.f, 0.f};

    for (int k0 = 0; k0 < KDIM; k0 += 32) {
        uint4 a0, a1, w0, w1;
        u16 e[16];
        if (!AIMG) {
            a0 = *(const uint4*)(pA0 + k0);
            a1 = *(const uint4*)(pA1 + k0);
        } else {
            const int kk2 = t & 31;
            const int tg = t >> 5;
            const u16* src = A + ((size_t)b * KDIM + k0 + kk2) * NTOK + m0 + tg * 16;
            *(uint4*)&e[0] = *(const uint4*)src;
            *(uint4*)&e[8] = *(const uint4*)(src + 8);
        }
        w0 = *(const uint4*)(pW0 + k0);
        w1 = *(const uint4*)(pW1 + k0);
        __syncthreads();
        if (!AIMG) {
            *(uint4*)&As[srow * 40 + sko] = a0;
            *(uint4*)&As[(64 + srow) * 40 + sko] = a1;
        } else {
            const int kk2 = t & 31;
            const int tg = t >> 5;
            #pragma unroll
            for (int j = 0; j < 16; j++) As[(tg * 16 + j) * 40 + kk2] = e[j];
        }
        *(uint4*)&Ws[srow * 40 + sko] = w0;
        *(uint4*)&Ws[(64 + srow) * 40 + sko] = w1;
        __syncthreads();
        bf16x8 af[4], bfv[4];
        #pragma unroll
        for (int i = 0; i < 4; i++)
            af[i] = *(bf16x8*)&As[(wm + i * 16 + (lane & 15)) * 40 + (lane >> 4) * 8];
        #pragma unroll
        for (int j = 0; j < 4; j++)
            bfv[j] = *(bf16x8*)&Ws[(wn + j * 16 + (lane & 15)) * 40 + (lane >> 4) * 8];
        #pragma unroll
        for (int i = 0; i < 4; i++)
            #pragma unroll
            for (int j = 0; j < 4; j++)
                acc[i][j] = __builtin_amdgcn_mfma_f32_16x16x32_bf16(af[i], bfv[j], acc[i][j], 0, 0, 0);
    }

    const int c2 = lane & 15, gq2 = lane >> 4;
    int colj[4];
    #pragma unroll
    for (int j = 0; j < 4; j++) colj[j] = n0 + wn + j * 16 + c2;

    if (LN2F) {
        #pragma unroll
        for (int i = 0; i < 4; i++) {
            int rbase = m0 + wm + i * 16 + gq2 * 4;
            #pragma unroll
            for (int j = 0; j < 4; j++) {
                const float* rf = (const float*)resid;
                float4 rr = *(const float4*)&rf[((size_t)b * NOUT + colj[j]) * NTOK + rbase];
                acc[i][j][0] += rr.x; acc[i][j][1] += rr.y;
                acc[i][j][2] += rr.z; acc[i][j][3] += rr.w;
            }
        }
        __syncthreads();                      // all waves done with As/Ws frag reads
        float* ps = (float*)&As[0];           // [2 halves][128 rows][2] = 2 KB, overlays As
        const int h = wn >> 6;
        float mean_[4][4], rstd_[4][4];
        #pragma unroll
        for (int i = 0; i < 4; i++)
            #pragma unroll
            for (int r = 0; r < 4; r++) {
                float s = 0.f, q = 0.f;
                #pragma unroll
                for (int j = 0; j < 4; j++) { float tv = acc[i][j][r]; s += tv; q += tv * tv; }
                s += __shfl_xor(s, 1, 64); q += __shfl_xor(q, 1, 64);
                s += __shfl_xor(s, 2, 64); q += __shfl_xor(q, 2, 64);
                s += __shfl_xor(s, 4, 64); q += __shfl_xor(q, 4, 64);
                s += __shfl_xor(s, 8, 64); q += __shfl_xor(q, 8, 64);
                if (c2 == 0) {
                    int rl = wm + i * 16 + gq2 * 4 + r;
                    ps[(h * 128 + rl) * 2 + 0] = s;
                    ps[(h * 128 + rl) * 2 + 1] = q;
                }
            }
        __syncthreads();
        #pragma unroll
        for (int i = 0; i < 4; i++)
            #pragma unroll
            for (int r = 0; r < 4; r++) {
                int rl = wm + i * 16 + gq2 * 4 + r;
                float s = ps[rl * 2 + 0] + ps[(128 + rl) * 2 + 0];
                float q = ps[rl * 2 + 1] + ps[(128 + rl) * 2 + 1];
                float mn = s * (1.0f / 128.0f);
                float vr = q * (1.0f / 128.0f) - mn * mn;
                mean_[i][r] = mn;
                rstd_[i][r] = rsqrtf(vr + 1e-5f);
            }
        float lwj[4], lbj[4];
        #pragma unroll
        for (int j = 0; j < 4; j++) { lwj[j] = lnw[colj[j]]; lbj[j] = lnb[colj[j]]; }
        u16* xo = (u16*)Cout;
        u16* mo = (u16*)Cout2;
        #pragma unroll
        for (int i = 0; i < 4; i++) {
            int rbase = m0 + wm + i * 16 + gq2 * 4;
            #pragma unroll
            for (int j = 0; j < 4; j++)
                #pragma unroll
                for (int r = 0; r < 4; r++) {
                    float tv = acc[i][j][r];
                    size_t off = ((size_t)b * NTOK + rbase + r) * NOUT + colj[j];
                    xo[off] = f2b(tv);
                    mo[off] = f2b((tv - mean_[i][r]) * rstd_[i][r] * lwj[j] + lbj[j]);
                }
        }
        return;
    }

    const float smul = (blockIdx.y == 0) ? ascale : 1.0f;
    float bj[4];
    #pragma unroll
    for (int j = 0; j < 4; j++) bj[j] = BIASF ? bias[colj[j]] : 0.f;
    #pragma unroll
    for (int i = 0; i < 4; i++) {
        int rbase = m0 + wm + i * 16 + gq2 * 4;
        #pragma unroll
        for (int j = 0; j < 4; j++) {
            f32x4 v = acc[i][j];
            v[0] *= smul; v[1] *= smul; v[2] *= smul; v[3] *= smul;
            if (BIASF) { v[0] += bj[j]; v[1] += bj[j]; v[2] += bj[j]; v[3] += bj[j]; }
            if (GELUF) { v[0] = gelu_f(v[0]); v[1] = gelu_f(v[1]); v[2] = gelu_f(v[2]); v[3] = gelu_f(v[3]); }
            if (RES == 1) {
                const float* rf = (const float*)resid;
                float4 rr = *(const float4*)&rf[((size_t)b * NOUT + colj[j]) * NTOK + rbase];
                v[0] += rr.x; v[1] += rr.y; v[2] += rr.z; v[3] += rr.w;
            } else if (RES == 3) {
                const u16* rb = (const u16*)resid;
                #pragma unroll
                for (int r = 0; r < 4; r++)
                    v[r] += b2f(rb[((size_t)b * NTOK + rbase + r) * NOUT + colj[j]]);
            }
            if (STIMG) {
                size_t off = ((size_t)b * NOUT + colj[j]) * NTOK + rbase;
                if (CBF) {
                    ushort4 o;
                    o.x = f2b(v[0]); o.y = f2b(v[1]); o.z = f2b(v[2]); o.w = f2b(v[3]);
                    *(ushort4*)((u16*)Cout + off) = o;
                } else {
                    *(float4*)((float*)Cout + off) = make_float4(v[0], v[1], v[2], v[3]);
                }
            } else {
                if (CBF) {
                    #pragma unroll
                    for (int r = 0; r < 4; r++)
                        ((u16*)Cout)[((size_t)b * NTOK + rbase + r) * NOUT + colj[j]] = f2b(v[r]);
                } else {
                    #pragma unroll
                    for (int r = 0; r < 4; r++)
                        ((float*)Cout)[((size_t)b * NTOK + rbase + r) * NOUT + colj[j]] = v[r];
                }
            }
        }
    }
}

// ---------------- MFMA windowed + global attention ----------------
// qkv: [B][NTOK][384] bf16 (q prescaled by log2e/sqrt(32)), sorted domain
// Softmax uses raw v_exp_f32 (2^x) via __builtin_amdgcn_exp2f.
// Pb shrunk to [64][32] with XOR col swizzle (col ^ ((row&3)<<3)):
// bank-balanced for uint2 writes and b128 reads, 16B alignment preserved,
// and total LDS drops 54272 -> 50176 B => 3 blocks/CU (was 2).
// block = (group, head-pair, batch); 4 waves: wave = (qhalf<<1) | local-head
__global__ __launch_bounds__(256, 3) void k_attn(const u16* __restrict__ qkv,
        const u16* __restrict__ kgbb, const u16* __restrict__ vgtb,
        u16* __restrict__ outp) {
    __shared__ u16 VT[2][32][264];   // V^T per local head: [dv][key 0..255 local, 256..263 global]
    __shared__ u16 Pb[4][64][32];    // per-wave P buffer [q][key], XOR-swizzled cols
    const int g = blockIdx.x, hp = blockIdx.y, b = blockIdx.z;
    const int t = threadIdx.x;
    const int wave = t >> 6, lane = t & 63;
    const int c = lane & 15, gq = lane >> 4;
    const int lh = wave & 1, head = hp * 2 + lh, qh = wave >> 1;
    const size_t brow = (size_t)b * NTOK;
    const bool lastg = (g == NGRP - 1);
    const int csw = (c & 3) << 3;    // XOR swizzle term (row&3 == c&3 for all P rows)

    {   // stage V^T (local window keys)
        int key = t;
        int pos = (!lastg || key < GSZ) ? g * GSZ + key : NTOK - 1 - (key - GSZ);
        const u16* vp = qkv + (brow + pos) * 384 + 256 + hp * 64;
        #pragma unroll
        for (int i = 0; i < 8; i++) {
            uint4 v = *(const uint4*)(vp + i * 8);
            u16 e[8];
            *(uint4*)e = v;
            #pragma unroll
            for (int j = 0; j < 8; j++) {
                int d = i * 8 + j;
                VT[d >> 5][d & 31][key] = e[j];
            }
        }
        if (t < 64) {   // global V^T -> keys 256..263
            int l2 = t >> 5, dv = t & 31;
            uint4 v = *(const uint4*)(vgtb + ((size_t)(hp * 2 + l2) * 32 + dv) * 8);
            *(uint4*)&VT[l2][dv][256] = v;
        }
    }

    // prefetch Q, ALL K fragments, and global-K before the barrier
    const int q0 = g * GSZ + qh * 64;
    bf16x8 qf[4];
    #pragma unroll
    for (int nq = 0; nq < 4; nq++)
        qf[nq] = *(const bf16x8*)(qkv + (brow + q0 + nq * 16 + c) * 384 + head * 32 + gq * 8);

    const u16* kbp = qkv + brow * 384 + 128 + head * 32 + gq * 8;
    bf16x8 kfa[8][2];
    #pragma unroll
    for (int s = 0; s < 8; s++)
        #pragma unroll
        for (int mk = 0; mk < 2; mk++) {
            int kl = s * 32 + mk * 16 + c;
            int pos = (!lastg || kl < GSZ) ? g * GSZ + kl : NTOK - 1 - (kl - GSZ);
            kfa[s][mk] = *(const bf16x8*)(kbp + (size_t)pos * 384);
        }
    bf16x8 kgf = *(const bf16x8*)(kgbb + (c & 7) * 128 + head * 32 + gq * 8);

    __syncthreads();

    f32x4 acc[4][2];
    #pragma unroll
    for (int i = 0; i < 4; i++)
        #pragma unroll
        for (int j = 0; j < 2; j++) acc[i][j] = (f32x4){0.f, 0.f, 0.f, 0.f};
    float lsum[4] = {0.f, 0.f, 0.f, 0.f};

    for (int s = 0; s < 8; s++) {
        // S^T = K x Q^T : lane holds 4 consecutive keys for q-col c
        #pragma unroll
        for (int mk = 0; mk < 2; mk++) {
            #pragma unroll
            for (int nq = 0; nq < 4; nq++) {
                f32x4 st = __builtin_amdgcn_mfma_f32_16x16x32_bf16(kfa[s][mk], qf[nq],
                        (f32x4){0.f, 0.f, 0.f, 0.f}, 0, 0, 0);
                float p0 = exp2_raw(st[0]), p1 = exp2_raw(st[1]);
                float p2 = exp2_raw(st[2]), p3 = exp2_raw(st[3]);
                lsum[nq] += (p0 + p1) + (p2 + p3);
                u32 r0, r1;
                asm("v_cvt_pk_bf16_f32 %0, %1, %2" : "=v"(r0) : "v"(p0), "v"(p1));
                asm("v_cvt_pk_bf16_f32 %0, %1, %2" : "=v"(r1) : "v"(p2), "v"(p3));
                *(uint2*)&Pb[wave][nq * 16 + c][(mk * 16 + gq * 4) ^ csw] = make_uint2(r0, r1);
            }
        }
        __builtin_amdgcn_sched_barrier(0);   // pin P-stores before pf ds_reads
        // PV
        bf16x8 pf[4], vf[2];
        #pragma unroll
        for (int mt = 0; mt < 4; mt++)
            pf[mt] = *(const bf16x8*)&Pb[wave][mt * 16 + c][(gq * 8) ^ csw];
        #pragma unroll
        for (int nv = 0; nv < 2; nv++)
            vf[nv] = *(const bf16x8*)&VT[lh][nv * 16 + c][s * 32 + gq * 8];
        #pragma unroll
        for (int mt = 0; mt < 4; mt++)
            #pragma unroll
            for (int nv = 0; nv < 2; nv++)
                acc[mt][nv] = __builtin_amdgcn_mfma_f32_16x16x32_bf16(pf[mt], vf[nv], acc[mt][nv], 0, 0, 0);
    }

    #pragma unroll
    for (int nq = 0; nq < 4; nq++) {
        lsum[nq] += __shfl_xor(lsum[nq], 16, 64);
        lsum[nq] += __shfl_xor(lsum[nq], 32, 64);
    }

    // global (IRCA means) step: 8 keys (+8 dup rows masked), P pre-weighted by l_local/l_global
    {
        #pragma unroll
        for (int nq = 0; nq < 4; nq++) {
            f32x4 sg = __builtin_amdgcn_mfma_f32_16x16x32_bf16(kgf, qf[nq],
                    (f32x4){0.f, 0.f, 0.f, 0.f}, 0, 0, 0);
            float p0, p1, p2, p3;
            if (gq < 2) {
                p0 = exp2_raw(sg[0]); p1 = exp2_raw(sg[1]);
                p2 = exp2_raw(sg[2]); p3 = exp2_raw(sg[3]);
            } else { p0 = p1 = p2 = p3 = 0.f; }
            float lg = (p0 + p1) + (p2 + p3);
            lg += __shfl_xor(lg, 16, 64);
            lg += __shfl_xor(lg, 32, 64);
            float w = lsum[nq] / lg;
            p0 *= w; p1 *= w; p2 *= w; p3 *= w;
            u32 r0, r1;
            asm("v_cvt_pk_bf16_f32 %0, %1, %2" : "=v"(r0) : "v"(p0), "v"(p1));
            asm("v_cvt_pk_bf16_f32 %0, %1, %2" : "=v"(r1) : "v"(p2), "v"(p3));
            *(uint2*)&Pb[wave][nq * 16 + c][(gq * 4) ^ csw] = make_uint2(r0, r1);
        }
        __builtin_amdgcn_sched_barrier(0);   // pin P-stores before pf ds_reads
        bf16x8 zf;
        #pragma unroll
        for (int z8 = 0; z8 < 8; z8++) zf[z8] = 0;
        bf16x8 pf[4], vf[2];
        #pragma unroll
        for (int mt = 0; mt < 4; mt++)
            pf[mt] = *(const bf16x8*)&Pb[wave][mt * 16 + c][(gq * 8) ^ csw];
        #pragma unroll
        for (int nv = 0; nv < 2; nv++)
            vf[nv] = (gq == 0) ? *(const bf16x8*)&VT[lh][nv * 16 + c][256] : zf;
        #pragma unroll
        for (int mt = 0; mt < 4; mt++)
            #pragma unroll
            for (int nv = 0; nv < 2; nv++)
                acc[mt][nv] = __builtin_amdgcn_mfma_f32_16x16x32_bf16(pf[mt], vf[nv], acc[mt][nv], 0, 0, 0);
    }

    // broadcast l via (dead) Pb region, then normalize into registers
    float* lf = (float*)&Pb[wave][0][0];
    if (gq == 0) {
        #pragma unroll
        for (int nq = 0; nq < 4; nq++) lf[nq * 16 + c] = lsum[nq];
    }
    __builtin_amdgcn_sched_barrier(0);       // pin lf stores before lf reads
    u16 ov[4][2][4];
    #pragma unroll
    for (int mt = 0; mt < 4; mt++) {
        float il[4];
        #pragma unroll
        for (int r = 0; r < 4; r++)
            il[r] = 1.f / lf[mt * 16 + gq * 4 + r];
        #pragma unroll
        for (int nv = 0; nv < 2; nv++)
            #pragma unroll
            for (int r = 0; r < 4; r++)
                ov[mt][nv][r] = f2b(acc[mt][nv][r] * il[r]);
    }

    // stage out-tile [128 rows][64 ch] into LDS (reuse VT; pad 68 -> 2 lanes/bank, free)
    __syncthreads();                         // all waves done reading VT/Pb
    u16* st = (u16*)&VT[0][0][0];            // [128][68]
    #pragma unroll
    for (int mt = 0; mt < 4; mt++)
        #pragma unroll
        for (int nv = 0; nv < 2; nv++)
            #pragma unroll
            for (int r = 0; r < 4; r++)
                st[(qh * 64 + mt * 16 + gq * 4 + r) * 68 + lh * 32 + nv * 16 + c] = ov[mt][nv][r];
    __syncthreads();
    // cooperative stores: 8 consecutive lanes cover one FULL 128 B line per instr
    {
        const int rl0 = t >> 3;              // 0..31
        const int seg = t & 7;
        #pragma unroll
        for (int p = 0; p < 4; p++) {
            int rl = rl0 + p * 32;
            uint4 v4 = *(const uint4*)&st[rl * 68 + seg * 8];
            *(uint4*)&outp[(brow + g * GSZ + rl) * 128 + hp * 64 + seg * 8] = v4;
        }
    }
}

// ---------------- depthwise 5x5 conv + bias + gelu + h1-add, vectorized ----------------
__global__ __launch_bounds__(256) void k_dw(const u16* __restrict__ himg,
        const float* __restrict__ dww, const float* __restrict__ dwb, u16* __restrict__ dsum) {
    const int mc = blockIdx.y, b = blockIdx.z;
    const int t = threadIdx.x;
    const int y = blockIdx.x * 32 + (t >> 4) * 2;   // output rows y, y+1
    const int xb = (t & 15) * 8;
    float wgt[25];
    #pragma unroll
    for (int i = 0; i < 25; i++) wgt[i] = dww[mc * 25 + i];
    const float bsv = dwb[mc];
    const u16* src = himg + ((size_t)b * MLPD + mc) * NTOK;
    u16* dst = dsum + ((size_t)b * MLPD + mc) * NTOK;

    float w[6][12];   // rows y-2..y+3, cols xb-2..xb+9 (fully static indexing)
    #pragma unroll
    for (int r = 0; r < 6; r++) {
        int ysrc = y - 2 + r;
        bool vy = (ysrc >= 0 && ysrc < HH);
        const u16* rp = src + ysrc * WW + xb;
        uint4 aq = vy ? *(const uint4*)(rp - 8) : make_uint4(0u, 0u, 0u, 0u);
        uint4 bq = vy ? *(const uint4*)(rp)     : make_uint4(0u, 0u, 0u, 0u);
        uint4 cq = vy ? *(const uint4*)(rp + 8) : make_uint4(0u, 0u, 0u, 0u);
        w[r][0]  = ulo(aq.w); w[r][1]  = uhi(aq.w);
        w[r][2]  = ulo(bq.x); w[r][3]  = uhi(bq.x);
        w[r][4]  = ulo(bq.y); w[r][5]  = uhi(bq.y);
        w[r][6]  = ulo(bq.z); w[r][7]  = uhi(bq.z);
        w[r][8]  = ulo(bq.w); w[r][9]  = uhi(bq.w);
        w[r][10] = ulo(cq.x); w[r][11] = uhi(cq.x);
        if (xb == 0)   { w[r][0]  = 0.f; w[r][1]  = 0.f; }
        if (xb == 120) { w[r][10] = 0.f; w[r][11] = 0.f; }
    }

    float acc0[8], acc1[8];
    #pragma unroll
    for (int px = 0; px < 8; px++) { acc0[px] = 0.f; acc1[px] = 0.f; }
    #pragma unroll
    for (int dy = 0; dy < 5; dy++)
        #pragma unroll
        for (int dx = 0; dx < 5; dx++) {
            float wv = wgt[dy * 5 + dx];
            #pragma unroll
            for (int px = 0; px < 8; px++) {
                acc0[px] = fmaf(wv, w[dy][px + dx], acc0[px]);
                acc1[px] = fmaf(wv, w[dy + 1][px + dx], acc1[px]);
            }
        }

    u32 o0[4], o1[4];
    #pragma unroll
    for (int px = 0; px < 8; px += 2) {
        u16 a0 = f2b(w[2][px + 2] + gelu_f(acc0[px] + bsv));
        u16 a1 = f2b(w[2][px + 3] + gelu_f(acc0[px + 1] + bsv));
        o0[px >> 1] = (u32)a0 | ((u32)a1 << 16);
        u16 b0 = f2b(w[3][px + 2] + gelu_f(acc1[px] + bsv));
        u16 b1 = f2b(w[3][px + 3] + gelu_f(acc1[px + 1] + bsv));
        o1[px >> 1] = (u32)b0 | ((u32)b1 << 16);
    }
    *(uint4*)(dst + y * WW + xb) = *(uint4*)o0;
    *(uint4*)(dst + (y + 1) * WW + xb) = *(uint4*)o1;
}

extern "C" void kernel_launch(void* const* d_in, const int* in_sizes, int n_in,
                              void* d_out, int out_size, void* d_ws, size_t ws_size,
                              hipStream_t stream) {
    const float* x       = (const float*)d_in[0];
    const float* means   = (const float*)d_in[1];
    const float* ln1_w   = (const float*)d_in[2];
    const float* ln1_b   = (const float*)d_in[3];
    const float* wq      = (const float*)d_in[4];
    const float* wk      = (const float*)d_in[5];
    const float* wv      = (const float*)d_in[6];
    const float* wproj   = (const float*)d_in[7];
    const float* irca_wk = (const float*)d_in[8];
    const float* irca_wv = (const float*)d_in[9];
    const float* conv1w  = (const float*)d_in[10];
    const float* ln2_w   = (const float*)d_in[11];
    const float* ln2_b   = (const float*)d_in[12];
    const float* fc1_w   = (const float*)d_in[13];
    const float* fc1_b   = (const float*)d_in[14];
    const float* dw_w    = (const float*)d_in[15];
    const float* dw_b    = (const float*)d_in[16];
    const float* fc2_w   = (const float*)d_in[17];
    const float* fc2_b   = (const float*)d_in[18];
    float* out = (float*)d_out;

    const size_t need = 202514432;
    if (ws_size < need) return;

    char* base = (char*)d_ws;
    float* mhat  = (float*)(base);                 // 4096 B
    u16*   kgbb  = (u16*)(base + 4096);            // 2048 B
    u16*   vgtb  = (u16*)(base + 6144);            // 2048 B
    int*   bucket = (int*)(base + 8192);           // 524288 B (weights+iinv overlay after sort)
    u16*   wqkv  = (u16*)(base + 8192);            // 98304 B (wq|wk|wv stacked)
    u16*   wfub  = wqkv + 3 * 16384;               // 32768 B
    u16*   fc1b  = wfub + 16384;                   // 65536 B
    u16*   fc2b  = fc1b + 32768;                   // 65536 B
    u16*   iinv  = (u16*)(base + 270336);          // 262144 B (hole after fc2b, inside dead bucket)
    int*   cnt   = (int*)(base + 532480);
    int*   cbase = (int*)(base + 598016);
    int*   gidx  = (int*)(base + 663552);
    u16*   Abase = (u16*)(base + 1187840);         // 100663296 B: qkv -> {himg, xmb}
    u16*   x2b   = (u16*)(base + 101851136);       // 33554432 B
    u16*   dsum  = (u16*)(base + 135405568);       // 67108864 B

    u16* qkv  = Abase;                 // [B][NTOK][384]
    u16* himg = Abase;                 // [B][256][NTOK] (after qkv dead)
    u16* xmb  = Abase + 2 * BIG;       // [B][NTOK][128]
    u16* xnb   = (u16*)d_out;          // LN1 out (d_out scratch)
    u16* attnb = (u16*)d_out;          // attention out, SORTED order (overwrites xnb)

    k_prep<<<NTm, 128, 0, stream>>>(means, irca_wk, irca_wv, mhat, kgbb, vgtb);
    k_ln1<<<BB * NTOK / 64, 256, 0, stream>>>(x, ln1_w, ln1_b, mhat, xnb, bucket);
    k_count<<<BB * NTOK / 64, 64, 0, stream>>>(bucket, cnt);
    k_scan<<<BB, 64, 0, stream>>>(cnt, cbase);
    k_place<<<BB * NTOK / 64, 64, 0, stream>>>(bucket, cbase, gidx);
    k_inv<<<BB * NTOK / 256, 256, 0, stream>>>(gidx, iinv);

    // weight conversions (bucket region is dead now)
    k_cvtall<<<448, 256, 0, stream>>>(wq, wk, wv, fc1_w, fc2_w, wqkv, fc1b, fc2b);
    k_fuse<<<64, 256, 0, stream>>>(conv1w, wproj, wfub);

    // q prescale includes log2(e): attn softmax uses raw v_exp_f32 (2^x)
    const float qsc2 = 0.25503489924160945f;  // (1/sqrt(32)) * log2(e)
    // fused gathered QKV: [B][NTOK][384]
    g_mfma<128, 384, 1, 0, 0, 0, 0, 0, 1, 0><<<dim3(128, 3, BB), 256, 0, stream>>>(
        xnb, wqkv, nullptr, nullptr, gidx, qkv, qsc2, nullptr, nullptr, nullptr);

    k_attn<<<dim3(NGRP, 2, BB), 256, 0, stream>>>(qkv, kgbb, vgtb, attnb);

    // x2 = x_img + gather(attn_sorted, iinv) @ Wfused^T, fused LN2:
    // writes x2b AND xmb (bf16 token)
    g_mfma<128, 128, 2, 0, 0, 0, 1, 0, 1, 1><<<dim3(128, 1, BB), 256, 0, stream>>>(
        attnb, wfub, nullptr, x, (const int*)iinv, x2b, 1.0f, ln2_w, ln2_b, xmb);

    g_mfma<128, 256, 0, 0, 1, 1, 0, 1, 1, 0><<<dim3(128, 2, BB), 256, 0, stream>>>(
        xmb, fc1b, fc1_b, nullptr, nullptr, himg, 1.0f, nullptr, nullptr, nullptr);
    k_dw<<<dim3(4, MLPD, BB), 256, 0, stream>>>(himg, dw_w, dw_b, dsum);
    // fc2 from image-layout dsum, + bf16 token resid x2, fp32 image out
    g_mfma<256, 128, 0, 1, 1, 0, 3, 1, 0, 0><<<dim3(128, 1, BB), 256, 0, stream>>>(
        dsum, fc2b, fc2_b, x2b, nullptr, out, 1.0f, nullptr, nullptr, nullptr);

    (void)in_sizes; (void)n_in; (void)out_size;
}

// Round 10
// 290.734 us; speedup vs baseline: 1.1757x; 1.0762x over previous
//
#include <hip/hip_runtime.h>
#include <math.h>

typedef unsigned short u16;
typedef unsigned int u32;
typedef __attribute__((ext_vector_type(8))) short bf16x8;
typedef __attribute__((ext_vector_type(4))) float f32x4;

constexpr int BB   = 8;
constexpr int DIMC = 128;
constexpr int HH   = 128;
constexpr int WW   = 128;
constexpr int NTOK = HH * WW;       // 16384
constexpr int QKD  = 128;
constexpr int MLPD = 256;
constexpr int NTm  = 8;
constexpr int GSZ  = 128;
constexpr int NGRP = NTOK / GSZ;    // 128
constexpr size_t BIG = 16777216;    // 8*16384*128 elements

// raw v_exp_f32 (2^x) via the compiler-known intrinsic: correct trans-op
// hazard handling; none of libm exp2f's OCML fixup code.
__device__ __forceinline__ float exp2_raw(float x) {
    return __builtin_amdgcn_exp2f(x);
}
// tanh-form GELU via raw HW exp2/rcp: ~8 VALU ops vs OCML erff's ~40-50
// (k_dw was erf-dominated, VALUBusy 81%). |err| vs exact-erf gelu ~1e-3,
// well inside the 0.108 absmax budget (current 0.031).
__device__ __forceinline__ float gelu_f(float v) {
    float u = v * (0.7978845608028654f + 0.035677408136300125f * v * v);
    float e = exp2_raw(u * 2.885390081777927f);          // e^(2u)
    float th = 1.0f - 2.0f * __builtin_amdgcn_rcpf(e + 1.0f);
    return 0.5f * v * (1.0f + th);
}
__device__ __forceinline__ float b2f(u16 u) {
    return __uint_as_float(((u32)u) << 16);
}
__device__ __forceinline__ u16 f2b(float f) {
    u32 x = __float_as_uint(f);
    return (u16)((x + 0x7fffu + ((x >> 16) & 1u)) >> 16);
}
__device__ __forceinline__ float ulo(u32 u) { return __uint_as_float(u << 16); }
__device__ __forceinline__ float uhi(u32 u) { return __uint_as_float(u & 0xffff0000u); }

// ---------------- prep: normalized means (fp32), global K (bf16), global V^T (bf16) ----------------
__global__ __launch_bounds__(128) void k_prep(const float* __restrict__ means,
        const float* __restrict__ iwk, const float* __restrict__ iwv,
        float* __restrict__ mhat, u16* __restrict__ kgbb, u16* __restrict__ vgtb) {
    __shared__ float sm[DIMC];
    __shared__ float inv_s;
    int tt = blockIdx.x;          // mean row 0..7
    int t = threadIdx.x;          // 0..127
    sm[t] = means[tt * DIMC + t];
    __syncthreads();
    if (t == 0) {
        float s = 0.f;
        for (int c = 0; c < DIMC; c++) s += sm[c] * sm[c];
        inv_s = 1.f / fmaxf(sqrtf(s), 1e-12f);
    }
    __syncthreads();
    mhat[tt * DIMC + t] = sm[t] * inv_s;
    float sk = 0.f, sv = 0.f;
    #pragma unroll 8
    for (int c = 0; c < DIMC; c++) {
        sk = fmaf(sm[c], iwk[t * DIMC + c], sk);
        sv = fmaf(sm[c], iwv[t * DIMC + c], sv);
    }
    kgbb[tt * DIMC + t] = f2b(sk);
    vgtb[(t >> 5) * 256 + (t & 31) * 8 + tt] = f2b(sv);   // [head][dv][8]
}

// ---------------- all weight converts fp32->bf16 in one launch ----------------
__global__ __launch_bounds__(256) void k_cvtall(const float* __restrict__ wq,
        const float* __restrict__ wk, const float* __restrict__ wv,
        const float* __restrict__ fc1, const float* __restrict__ fc2,
        u16* __restrict__ wqkv, u16* __restrict__ fc1b, u16* __restrict__ fc2b) {
    int i = blockIdx.x * 256 + threadIdx.x;
    if (i < 49152) {
        const float* s = (i < 16384) ? wq : (i < 32768 ? wk : wv);
        wqkv[i] = f2b(s[i & 16383]);
    } else if (i < 81920) {
        fc1b[i - 49152] = f2b(fc1[i - 49152]);
    } else if (i < 114688) {
        fc2b[i - 81920] = f2b(fc2[i - 81920]);
    }
}

// ---------------- fused conv1x1 @ wproj ----------------
__global__ __launch_bounds__(256) void k_fuse(const float* __restrict__ c1,
        const float* __restrict__ wp, u16* __restrict__ wf) {
    __shared__ float wpS[DIMC * DIMC];
    int t = threadIdx.x;
    for (int i = t; i < DIMC * DIMC; i += 256) wpS[i] = wp[i];
    __syncthreads();
    int o = blockIdx.x * 2 + (t >> 7);
    int c = t & 127;
    float s = 0.f;
    #pragma unroll 8
    for (int m = 0; m < DIMC; m++) s = fmaf(c1[o * DIMC + m], wpS[m * DIMC + c], s);
    wf[o * DIMC + c] = f2b(s);
}

// ---------------- LN1 + cluster scores + bucket (bf16 xn out), channel-split ----------------
__global__ __launch_bounds__(256) void k_ln1(const float* __restrict__ x,
        const float* __restrict__ lw, const float* __restrict__ lb,
        const float* __restrict__ mhat, u16* __restrict__ xn, int* __restrict__ bucket) {
    __shared__ float smh[NTm * DIMC];     // 4 KB
    __shared__ float lwb[DIMC], lbb[DIMC];
    __shared__ float red[4][64][3];       // sum, sq (+pad -> 2-way max)
    __shared__ float scr[4][64][9];       // partial scores (+pad -> 2-way max)
    const int chunk = blockIdx.x;         // 0..2047
    const int b = chunk >> 8;
    const int n0 = (chunk & 255) << 6;
    const int t = threadIdx.x;
    const int cg = t >> 6, tok = t & 63;
    const int n = n0 + tok;
    const int cbase = cg * 32;
    for (int i = t; i < NTm * DIMC; i += 256) smh[i] = mhat[i];
    if (t < DIMC) { lwb[t] = lw[t]; lbb[t] = lb[t]; }

    const float* xb = x + (size_t)b * DIMC * NTOK + (size_t)cbase * NTOK + n;
    float xv[32];
    float sum = 0.f, sq = 0.f;
    #pragma unroll
    for (int c = 0; c < 32; c++) {
        float v = xb[(size_t)c * NTOK];
        xv[c] = v;
        sum += v; sq += v * v;
    }
    red[cg][tok][0] = sum;
    red[cg][tok][1] = sq;
    __syncthreads();                      // covers smh/lwb staging + red
    float s0 = red[0][tok][0] + red[1][tok][0] + red[2][tok][0] + red[3][tok][0];
    float q0 = red[0][tok][1] + red[1][tok][1] + red[2][tok][1] + red[3][tok][1];
    float mean = s0 * (1.0f / DIMC);
    float var = q0 * (1.0f / DIMC) - mean * mean;
    float rstd = rsqrtf(var + 1e-5f);

    float sc[NTm];
    #pragma unroll
    for (int j = 0; j < NTm; j++) sc[j] = 0.f;
    u32 opk[16];
    #pragma unroll
    for (int c = 0; c < 32; c += 2) {
        float v0 = (xv[c]     - mean) * rstd * lwb[cbase + c]     + lbb[cbase + c];
        float v1 = (xv[c + 1] - mean) * rstd * lwb[cbase + c + 1] + lbb[cbase + c + 1];
        #pragma unroll
        for (int j = 0; j < NTm; j++) {
            sc[j] = fmaf(v0, smh[j * DIMC + cbase + c], sc[j]);
            sc[j] = fmaf(v1, smh[j * DIMC + cbase + c + 1], sc[j]);
        }
        opk[c >> 1] = (u32)f2b(v0) | ((u32)f2b(v1) << 16);
    }
    u16* xnr = xn + ((size_t)b * NTOK + n) * DIMC + cbase;
    *(uint4*)(xnr + 0)  = make_uint4(opk[0],  opk[1],  opk[2],  opk[3]);
    *(uint4*)(xnr + 8)  = make_uint4(opk[4],  opk[5],  opk[6],  opk[7]);
    *(uint4*)(xnr + 16) = make_uint4(opk[8],  opk[9],  opk[10], opk[11]);
    *(uint4*)(xnr + 24) = make_uint4(opk[12], opk[13], opk[14], opk[15]);

    #pragma unroll
    for (int j = 0; j < NTm; j++) scr[cg][tok][j] = sc[j];
    __syncthreads();
    if (cg == 0) {
        float v0 = ((scr[0][tok][0] + scr[1][tok][0]) + (scr[2][tok][0] + scr[3][tok][0]));
        int best = 0; float bv = v0;
        #pragma unroll
        for (int j = 1; j < NTm; j++) {
            float v = ((scr[0][tok][j] + scr[1][tok][j]) + (scr[2][tok][j] + scr[3][tok][j]));
            if (v > bv) { bv = v; best = j; }
        }
        bucket[b * NTOK + n] = best;
    }
}

// ---------------- stable counting sort ----------------
__global__ __launch_bounds__(64) void k_count(const int* __restrict__ bucket, int* __restrict__ cnt) {
    int chunk = blockIdx.x;
    int bk = bucket[(chunk << 6) + threadIdx.x];
    #pragma unroll
    for (int j = 0; j < NTm; j++) {
        unsigned long long m = __ballot(bk == j);
        if (threadIdx.x == 0) cnt[chunk * NTm + j] = (int)__popcll(m);
    }
}

__global__ __launch_bounds__(64) void k_scan(const int* __restrict__ cnt, int* __restrict__ base) {
    __shared__ int sc[256 * NTm];
    __shared__ int bb[NTm], tot[NTm];
    int b = blockIdx.x, t = threadIdx.x;
    for (int i = t; i < 256 * NTm; i += 64) sc[i] = cnt[b * 256 * NTm + i];
    __syncthreads();
    if (t < NTm) {
        int run = 0;
        for (int c = 0; c < 256; c++) {
            int v = sc[c * NTm + t];
            sc[c * NTm + t] = run;
            run += v;
        }
        tot[t] = run;
    }
    __syncthreads();
    if (t == 0) {
        int a = 0;
        for (int j = 0; j < NTm; j++) { bb[j] = a; a += tot[j]; }
    }
    __syncthreads();
    for (int i = t; i < 256 * NTm; i += 64) base[b * 256 * NTm + i] = sc[i] + bb[i & 7];
}

__global__ __launch_bounds__(64) void k_place(const int* __restrict__ bucket,
        const int* __restrict__ base, int* __restrict__ gidx) {
    int chunk = blockIdx.x;
    int lane = threadIdx.x;
    int nf = (chunk << 6) + lane;
    int bk = bucket[nf];
    unsigned long long lower = (1ull << lane) - 1ull;
    int rank = 0;
    #pragma unroll
    for (int j = 0; j < NTm; j++) {
        unsigned long long m = __ballot(bk == j);
        if (bk == j) rank = (int)__popcll(m & lower);
    }
    int b = nf >> 14;
    int pos = base[chunk * NTm + bk] + rank;
    gidx[b * NTOK + pos] = nf & (NTOK - 1);
}

// ---------------- invert permutation: iinv[token] = sorted position (u16) ----------------
__global__ __launch_bounds__(256) void k_inv(const int* __restrict__ gidx, u16* __restrict__ iinv) {
    int i = blockIdx.x * 256 + threadIdx.x;   // 0 .. B*NTOK-1
    int b = i >> 14;
    iinv[((size_t)b << 14) + gidx[i]] = (u16)(i & (NTOK - 1));
}

// ---------------- MFMA bf16 GEMM: C[m][n] = sum_k A[m][k]*W[n][k] ----------------
// AIMG: A is bf16 image-layout [B][KDIM][NTOK] (stage with transpose)
// GATHER: 0 none, 1 int32 index (gidx), 2 u16 index (iinv)
// RES: 0 none, 1 fp32 image resid, 3 bf16 token resid
// STIMG: 1 = image-layout store; CBF: 1 = bf16 store, 0 = fp32
// LN2F: fused LayerNorm epilogue (requires NOUT=128, RES=1, grid.y=1)
// ascale multiplies acc when blockIdx.y==0 (used to pre-scale q)
template<int KDIM, int NOUT, int GATHER, int AIMG, int BIASF, int GELUF, int RES, int STIMG, int CBF, int LN2F>
__global__ __launch_bounds__(256) void g_mfma(const u16* __restrict__ A, const u16* __restrict__ W,
        const float* __restrict__ bias, const void* __restrict__ resid,
        const int* __restrict__ gidx, void* __restrict__ Cout, float ascale,
        const float* __restrict__ lnw, const float* __restrict__ lnb, void* __restrict__ Cout2) {
    __shared__ u16 As[128 * 40];
    __shared__ u16 Ws[128 * 40];
    const int b = blockIdx.z;
    const int m0 = blockIdx.x * 128;
    const int n0 = blockIdx.y * 128;
    const int t = threadIdx.x;
    const int lane = t & 63;
    const int wave = t >> 6;
    const int wm = (wave & 1) * 64;
    const int wn = (wave >> 1) * 64;
    const int srow = t >> 2;
    const int sko = (t & 3) * 8;
    const u16* pA0 = nullptr; const u16* pA1 = nullptr;
    if (!AIMG) {
        int ra0 = m0 + srow, ra1 = m0 + 64 + srow;
        if (GATHER == 1) {
            ra0 = gidx[b * NTOK + ra0];
            ra1 = gidx[b * NTOK + ra1];
        } else if (GATHER == 2) {
            const u16* gi = (const u16*)gidx;
            ra0 = gi[b * NTOK + ra0];
            ra1 = gi[b * NTOK + ra1];
        }
        pA0 = A + ((size_t)b * NTOK + ra0) * KDIM + sko;
        pA1 = A + ((size_t)b * NTOK + ra1) * KDIM + sko;
    }
    const u16* pW0 = W + (size_t)(n0 + srow) * KDIM + sko;
    const u16* pW1 = W + (size_t)(n0 + 64 + srow) * KDIM + sko;

    f32x4 acc[4][4];
    #pragma unroll
    for (int i = 0; i < 4; i++)
        #pragma unroll
        for (int j = 0; j < 4; j++) acc[i][j] = (f32x4){0.f, 0.f, 0.f, 0.f};

    for (int k0 = 0; k0 < KDIM; k0 += 32) {
        uint4 a0, a1, w0, w1;
        u16 e[16];
        if (!AIMG) {
            a0 = *(const uint4*)(pA0 + k0);
            a1 = *(const uint4*)(pA1 + k0);
        } else {
            const int kk2 = t & 31;
            const int tg = t >> 5;
            const u16* src = A + ((size_t)b * KDIM + k0 + kk2) * NTOK + m0 + tg * 16;
            *(uint4*)&e[0] = *(const uint4*)src;
            *(uint4*)&e[8] = *(const uint4*)(src + 8);
        }
        w0 = *(const uint4*)(pW0 + k0);
        w1 = *(const uint4*)(pW1 + k0);
        __syncthreads();
        if (!AIMG) {
            *(uint4*)&As[srow * 40 + sko] = a0;
            *(uint4*)&As[(64 + srow) * 40 + sko] = a1;
        } else {
            const int kk2 = t & 31;
            const int tg = t >> 5;
            #pragma unroll
            for (int j = 0; j < 16; j++) As[(tg * 16 + j) * 40 + kk2] = e[j];
        }
        *(uint4*)&Ws[srow * 40 + sko] = w0;
        *(uint4*)&Ws[(64 + srow) * 40 + sko] = w1;
        __syncthreads();
        bf16x8 af[4], bfv[4];
        #pragma unroll
        for (int i = 0; i < 4; i++)
            af[i] = *(bf16x8*)&As[(wm + i * 16 + (lane & 15)) * 40 + (lane >> 4) * 8];
        #pragma unroll
        for (int j = 0; j < 4; j++)
            bfv[j] = *(bf16x8*)&Ws[(wn + j * 16 + (lane & 15)) * 40 + (lane >> 4) * 8];
        #pragma unroll
        for (int i = 0; i < 4; i++)
            #pragma unroll
            for (int j = 0; j < 4; j++)
                acc[i][j] = __builtin_amdgcn_mfma_f32_16x16x32_bf16(af[i], bfv[j], acc[i][j], 0, 0, 0);
    }

    const int c2 = lane & 15, gq2 = lane >> 4;
    int colj[4];
    #pragma unroll
    for (int j = 0; j < 4; j++) colj[j] = n0 + wn + j * 16 + c2;

    if (LN2F) {
        #pragma unroll
        for (int i = 0; i < 4; i++) {
            int rbase = m0 + wm + i * 16 + gq2 * 4;
            #pragma unroll
            for (int j = 0; j < 4; j++) {
                const float* rf = (const float*)resid;
                float4 rr = *(const float4*)&rf[((size_t)b * NOUT + colj[j]) * NTOK + rbase];
                acc[i][j][0] += rr.x; acc[i][j][1] += rr.y;
                acc[i][j][2] += rr.z; acc[i][j][3] += rr.w;
            }
        }
        __syncthreads();                      // all waves done with As/Ws frag reads
        float* ps = (float*)&As[0];           // [2 halves][128 rows][2] = 2 KB, overlays As
        const int h = wn >> 6;
        float mean_[4][4], rstd_[4][4];
        #pragma unroll
        for (int i = 0; i < 4; i++)
            #pragma unroll
            for (int r = 0; r < 4; r++) {
                float s = 0.f, q = 0.f;
                #pragma unroll
                for (int j = 0; j < 4; j++) { float tv = acc[i][j][r]; s += tv; q += tv * tv; }
                s += __shfl_xor(s, 1, 64); q += __shfl_xor(q, 1, 64);
                s += __shfl_xor(s, 2, 64); q += __shfl_xor(q, 2, 64);
                s += __shfl_xor(s, 4, 64); q += __shfl_xor(q, 4, 64);
                s += __shfl_xor(s, 8, 64); q += __shfl_xor(q, 8, 64);
                if (c2 == 0) {
                    int rl = wm + i * 16 + gq2 * 4 + r;
                    ps[(h * 128 + rl) * 2 + 0] = s;
                    ps[(h * 128 + rl) * 2 + 1] = q;
                }
            }
        __syncthreads();
        #pragma unroll
        for (int i = 0; i < 4; i++)
            #pragma unroll
            for (int r = 0; r < 4; r++) {
                int rl = wm + i * 16 + gq2 * 4 + r;
                float s = ps[rl * 2 + 0] + ps[(128 + rl) * 2 + 0];
                float q = ps[rl * 2 + 1] + ps[(128 + rl) * 2 + 1];
                float mn = s * (1.0f / 128.0f);
                float vr = q * (1.0f / 128.0f) - mn * mn;
                mean_[i][r] = mn;
                rstd_[i][r] = rsqrtf(vr + 1e-5f);
            }
        float lwj[4], lbj[4];
        #pragma unroll
        for (int j = 0; j < 4; j++) { lwj[j] = lnw[colj[j]]; lbj[j] = lnb[colj[j]]; }
        u16* xo = (u16*)Cout;
        u16* mo = (u16*)Cout2;
        #pragma unroll
        for (int i = 0; i < 4; i++) {
            int rbase = m0 + wm + i * 16 + gq2 * 4;
            #pragma unroll
            for (int j = 0; j < 4; j++)
                #pragma unroll
                for (int r = 0; r < 4; r++) {
                    float tv = acc[i][j][r];
                    size_t off = ((size_t)b * NTOK + rbase + r) * NOUT + colj[j];
                    xo[off] = f2b(tv);
                    mo[off] = f2b((tv - mean_[i][r]) * rstd_[i][r] * lwj[j] + lbj[j]);
                }
        }
        return;
    }

    const float smul = (blockIdx.y == 0) ? ascale : 1.0f;
    float bj[4];
    #pragma unroll
    for (int j = 0; j < 4; j++) bj[j] = BIASF ? bias[colj[j]] : 0.f;
    #pragma unroll
    for (int i = 0; i < 4; i++) {
        int rbase = m0 + wm + i * 16 + gq2 * 4;
        #pragma unroll
        for (int j = 0; j < 4; j++) {
            f32x4 v = acc[i][j];
            v[0] *= smul; v[1] *= smul; v[2] *= smul; v[3] *= smul;
            if (BIASF) { v[0] += bj[j]; v[1] += bj[j]; v[2] += bj[j]; v[3] += bj[j]; }
            if (GELUF) { v[0] = gelu_f(v[0]); v[1] = gelu_f(v[1]); v[2] = gelu_f(v[2]); v[3] = gelu_f(v[3]); }
            if (RES == 1) {
                const float* rf = (const float*)resid;
                float4 rr = *(const float4*)&rf[((size_t)b * NOUT + colj[j]) * NTOK + rbase];
                v[0] += rr.x; v[1] += rr.y; v[2] += rr.z; v[3] += rr.w;
            } else if (RES == 3) {
                const u16* rb = (const u16*)resid;
                #pragma unroll
                for (int r = 0; r < 4; r++)
                    v[r] += b2f(rb[((size_t)b * NTOK + rbase + r) * NOUT + colj[j]]);
            }
            if (STIMG) {
                size_t off = ((size_t)b * NOUT + colj[j]) * NTOK + rbase;
                if (CBF) {
                    ushort4 o;
                    o.x = f2b(v[0]); o.y = f2b(v[1]); o.z = f2b(v[2]); o.w = f2b(v[3]);
                    *(ushort4*)((u16*)Cout + off) = o;
                } else {
                    *(float4*)((float*)Cout + off) = make_float4(v[0], v[1], v[2], v[3]);
                }
            } else {
                if (CBF) {
                    #pragma unroll
                    for (int r = 0; r < 4; r++)
                        ((u16*)Cout)[((size_t)b * NTOK + rbase + r) * NOUT + colj[j]] = f2b(v[r]);
                } else {
                    #pragma unroll
                    for (int r = 0; r < 4; r++)
                        ((float*)Cout)[((size_t)b * NTOK + rbase + r) * NOUT + colj[j]] = v[r];
                }
            }
        }
    }
}

// ---------------- MFMA windowed + global attention ----------------
// qkv: [B][NTOK][384] bf16 (q prescaled by log2e/sqrt(32)), sorted domain
// Softmax uses raw v_exp_f32 (2^x) via __builtin_amdgcn_exp2f.
// Pb [64][32] with XOR col swizzle; LDS 50176 B => 3 blocks/CU.
// block = (group, head-pair, batch); 4 waves: wave = (qhalf<<1) | local-head
__global__ __launch_bounds__(256, 3) void k_attn(const u16* __restrict__ qkv,
        const u16* __restrict__ kgbb, const u16* __restrict__ vgtb,
        u16* __restrict__ outp) {
    __shared__ u16 VT[2][32][264];   // V^T per local head: [dv][key 0..255 local, 256..263 global]
    __shared__ u16 Pb[4][64][32];    // per-wave P buffer [q][key], XOR-swizzled cols
    const int g = blockIdx.x, hp = blockIdx.y, b = blockIdx.z;
    const int t = threadIdx.x;
    const int wave = t >> 6, lane = t & 63;
    const int c = lane & 15, gq = lane >> 4;
    const int lh = wave & 1, head = hp * 2 + lh, qh = wave >> 1;
    const size_t brow = (size_t)b * NTOK;
    const bool lastg = (g == NGRP - 1);
    const int csw = (c & 3) << 3;    // XOR swizzle term (row&3 == c&3 for all P rows)

    {   // stage V^T (local window keys)
        int key = t;
        int pos = (!lastg || key < GSZ) ? g * GSZ + key : NTOK - 1 - (key - GSZ);
        const u16* vp = qkv + (brow + pos) * 384 + 256 + hp * 64;
        #pragma unroll
        for (int i = 0; i < 8; i++) {
            uint4 v = *(const uint4*)(vp + i * 8);
            u16 e[8];
            *(uint4*)e = v;
            #pragma unroll
            for (int j = 0; j < 8; j++) {
                int d = i * 8 + j;
                VT[d >> 5][d & 31][key] = e[j];
            }
        }
        if (t < 64) {   // global V^T -> keys 256..263
            int l2 = t >> 5, dv = t & 31;
            uint4 v = *(const uint4*)(vgtb + ((size_t)(hp * 2 + l2) * 32 + dv) * 8);
            *(uint4*)&VT[l2][dv][256] = v;
        }
    }

    // prefetch Q, ALL K fragments, and global-K before the barrier
    const int q0 = g * GSZ + qh * 64;
    bf16x8 qf[4];
    #pragma unroll
    for (int nq = 0; nq < 4; nq++)
        qf[nq] = *(const bf16x8*)(qkv + (brow + q0 + nq * 16 + c) * 384 + head * 32 + gq * 8);

    const u16* kbp = qkv + brow * 384 + 128 + head * 32 + gq * 8;
    bf16x8 kfa[8][2];
    #pragma unroll
    for (int s = 0; s < 8; s++)
        #pragma unroll
        for (int mk = 0; mk < 2; mk++) {
            int kl = s * 32 + mk * 16 + c;
            int pos = (!lastg || kl < GSZ) ? g * GSZ + kl : NTOK - 1 - (kl - GSZ);
            kfa[s][mk] = *(const bf16x8*)(kbp + (size_t)pos * 384);
        }
    bf16x8 kgf = *(const bf16x8*)(kgbb + (c & 7) * 128 + head * 32 + gq * 8);

    __syncthreads();

    f32x4 acc[4][2];
    #pragma unroll
    for (int i = 0; i < 4; i++)
        #pragma unroll
        for (int j = 0; j < 2; j++) acc[i][j] = (f32x4){0.f, 0.f, 0.f, 0.f};
    float lsum[4] = {0.f, 0.f, 0.f, 0.f};

    for (int s = 0; s < 8; s++) {
        // S^T = K x Q^T : lane holds 4 consecutive keys for q-col c
        #pragma unroll
        for (int mk = 0; mk < 2; mk++) {
            #pragma unroll
            for (int nq = 0; nq < 4; nq++) {
                f32x4 st = __builtin_amdgcn_mfma_f32_16x16x32_bf16(kfa[s][mk], qf[nq],
                        (f32x4){0.f, 0.f, 0.f, 0.f}, 0, 0, 0);
                float p0 = exp2_raw(st[0]), p1 = exp2_raw(st[1]);
                float p2 = exp2_raw(st[2]), p3 = exp2_raw(st[3]);
                lsum[nq] += (p0 + p1) + (p2 + p3);
                u32 r0, r1;
                asm("v_cvt_pk_bf16_f32 %0, %1, %2" : "=v"(r0) : "v"(p0), "v"(p1));
                asm("v_cvt_pk_bf16_f32 %0, %1, %2" : "=v"(r1) : "v"(p2), "v"(p3));
                *(uint2*)&Pb[wave][nq * 16 + c][(mk * 16 + gq * 4) ^ csw] = make_uint2(r0, r1);
            }
        }
        __builtin_amdgcn_sched_barrier(0);   // pin P-stores before pf ds_reads
        // PV
        bf16x8 pf[4], vf[2];
        #pragma unroll
        for (int mt = 0; mt < 4; mt++)
            pf[mt] = *(const bf16x8*)&Pb[wave][mt * 16 + c][(gq * 8) ^ csw];
        #pragma unroll
        for (int nv = 0; nv < 2; nv++)
            vf[nv] = *(const bf16x8*)&VT[lh][nv * 16 + c][s * 32 + gq * 8];
        #pragma unroll
        for (int mt = 0; mt < 4; mt++)
            #pragma unroll
            for (int nv = 0; nv < 2; nv++)
                acc[mt][nv] = __builtin_amdgcn_mfma_f32_16x16x32_bf16(pf[mt], vf[nv], acc[mt][nv], 0, 0, 0);
    }

    #pragma unroll
    for (int nq = 0; nq < 4; nq++) {
        lsum[nq] += __shfl_xor(lsum[nq], 16, 64);
        lsum[nq] += __shfl_xor(lsum[nq], 32, 64);
    }

    // global (IRCA means) step: 8 keys (+8 dup rows masked), P pre-weighted by l_local/l_global
    {
        #pragma unroll
        for (int nq = 0; nq < 4; nq++) {
            f32x4 sg = __builtin_amdgcn_mfma_f32_16x16x32_bf16(kgf, qf[nq],
                    (f32x4){0.f, 0.f, 0.f, 0.f}, 0, 0, 0);
            float p0, p1, p2, p3;
            if (gq < 2) {
                p0 = exp2_raw(sg[0]); p1 = exp2_raw(sg[1]);
                p2 = exp2_raw(sg[2]); p3 = exp2_raw(sg[3]);
            } else { p0 = p1 = p2 = p3 = 0.f; }
            float lg = (p0 + p1) + (p2 + p3);
            lg += __shfl_xor(lg, 16, 64);
            lg += __shfl_xor(lg, 32, 64);
            float w = lsum[nq] / lg;
            p0 *= w; p1 *= w; p2 *= w; p3 *= w;
            u32 r0, r1;
            asm("v_cvt_pk_bf16_f32 %0, %1, %2" : "=v"(r0) : "v"(p0), "v"(p1));
            asm("v_cvt_pk_bf16_f32 %0, %1, %2" : "=v"(r1) : "v"(p2), "v"(p3));
            *(uint2*)&Pb[wave][nq * 16 + c][(gq * 4) ^ csw] = make_uint2(r0, r1);
        }
        __builtin_amdgcn_sched_barrier(0);   // pin P-stores before pf ds_reads
        bf16x8 zf;
        #pragma unroll
        for (int z8 = 0; z8 < 8; z8++) zf[z8] = 0;
        bf16x8 pf[4], vf[2];
        #pragma unroll
        for (int mt = 0; mt < 4; mt++)
            pf[mt] = *(const bf16x8*)&Pb[wave][mt * 16 + c][(gq * 8) ^ csw];
        #pragma unroll
        for (int nv = 0; nv < 2; nv++)
            vf[nv] = (gq == 0) ? *(const bf16x8*)&VT[lh][nv * 16 + c][256] : zf;
        #pragma unroll
        for (int mt = 0; mt < 4; mt++)
            #pragma unroll
            for (int nv = 0; nv < 2; nv++)
                acc[mt][nv] = __builtin_amdgcn_mfma_f32_16x16x32_bf16(pf[mt], vf[nv], acc[mt][nv], 0, 0, 0);
    }

    // broadcast l via (dead) Pb region, then normalize into registers
    float* lf = (float*)&Pb[wave][0][0];
    if (gq == 0) {
        #pragma unroll
        for (int nq = 0; nq < 4; nq++) lf[nq * 16 + c] = lsum[nq];
    }
    __builtin_amdgcn_sched_barrier(0);       // pin lf stores before lf reads
    u16 ov[4][2][4];
    #pragma unroll
    for (int mt = 0; mt < 4; mt++) {
        float il[4];
        #pragma unroll
        for (int r = 0; r < 4; r++)
            il[r] = 1.f / lf[mt * 16 + gq * 4 + r];
        #pragma unroll
        for (int nv = 0; nv < 2; nv++)
            #pragma unroll
            for (int r = 0; r < 4; r++)
                ov[mt][nv][r] = f2b(acc[mt][nv][r] * il[r]);
    }

    // stage out-tile [128 rows][64 ch] into LDS (reuse VT; pad 68 -> 2 lanes/bank, free)
    __syncthreads();                         // all waves done reading VT/Pb
    u16* st = (u16*)&VT[0][0][0];            // [128][68]
    #pragma unroll
    for (int mt = 0; mt < 4; mt++)
        #pragma unroll
        for (int nv = 0; nv < 2; nv++)
            #pragma unroll
            for (int r = 0; r < 4; r++)
                st[(qh * 64 + mt * 16 + gq * 4 + r) * 68 + lh * 32 + nv * 16 + c] = ov[mt][nv][r];
    __syncthreads();
    // cooperative stores: 8 consecutive lanes cover one FULL 128 B line per instr
    {
        const int rl0 = t >> 3;              // 0..31
        const int seg = t & 7;
        #pragma unroll
        for (int p = 0; p < 4; p++) {
            int rl = rl0 + p * 32;
            uint4 v4 = *(const uint4*)&st[rl * 68 + seg * 8];
            *(uint4*)&outp[(brow + g * GSZ + rl) * 128 + hp * 64 + seg * 8] = v4;
        }
    }
}

// ---------------- depthwise 5x5 conv + bias + gelu + h1-add, vectorized ----------------
__global__ __launch_bounds__(256) void k_dw(const u16* __restrict__ himg,
        const float* __restrict__ dww, const float* __restrict__ dwb, u16* __restrict__ dsum) {
    const int mc = blockIdx.y, b = blockIdx.z;
    const int t = threadIdx.x;
    const int y = blockIdx.x * 32 + (t >> 4) * 2;   // output rows y, y+1
    const int xb = (t & 15) * 8;
    float wgt[25];
    #pragma unroll
    for (int i = 0; i < 25; i++) wgt[i] = dww[mc * 25 + i];
    const float bsv = dwb[mc];
    const u16* src = himg + ((size_t)b * MLPD + mc) * NTOK;
    u16* dst = dsum + ((size_t)b * MLPD + mc) * NTOK;

    float w[6][12];   // rows y-2..y+3, cols xb-2..xb+9 (fully static indexing)
    #pragma unroll
    for (int r = 0; r < 6; r++) {
        int ysrc = y - 2 + r;
        bool vy = (ysrc >= 0 && ysrc < HH);
        const u16* rp = src + ysrc * WW + xb;
        uint4 aq = vy ? *(const uint4*)(rp - 8) : make_uint4(0u, 0u, 0u, 0u);
        uint4 bq = vy ? *(const uint4*)(rp)     : make_uint4(0u, 0u, 0u, 0u);
        uint4 cq = vy ? *(const uint4*)(rp + 8) : make_uint4(0u, 0u, 0u, 0u);
        w[r][0]  = ulo(aq.w); w[r][1]  = uhi(aq.w);
        w[r][2]  = ulo(bq.x); w[r][3]  = uhi(bq.x);
        w[r][4]  = ulo(bq.y); w[r][5]  = uhi(bq.y);
        w[r][6]  = ulo(bq.z); w[r][7]  = uhi(bq.z);
        w[r][8]  = ulo(bq.w); w[r][9]  = uhi(bq.w);
        w[r][10] = ulo(cq.x); w[r][11] = uhi(cq.x);
        if (xb == 0)   { w[r][0]  = 0.f; w[r][1]  = 0.f; }
        if (xb == 120) { w[r][10] = 0.f; w[r][11] = 0.f; }
    }

    float acc0[8], acc1[8];
    #pragma unroll
    for (int px = 0; px < 8; px++) { acc0[px] = 0.f; acc1[px] = 0.f; }
    #pragma unroll
    for (int dy = 0; dy < 5; dy++)
        #pragma unroll
        for (int dx = 0; dx < 5; dx++) {
            float wv = wgt[dy * 5 + dx];
            #pragma unroll
            for (int px = 0; px < 8; px++) {
                acc0[px] = fmaf(wv, w[dy][px + dx], acc0[px]);
                acc1[px] = fmaf(wv, w[dy + 1][px + dx], acc1[px]);
            }
        }

    u32 o0[4], o1[4];
    #pragma unroll
    for (int px = 0; px < 8; px += 2) {
        u16 a0 = f2b(w[2][px + 2] + gelu_f(acc0[px] + bsv));
        u16 a1 = f2b(w[2][px + 3] + gelu_f(acc0[px + 1] + bsv));
        o0[px >> 1] = (u32)a0 | ((u32)a1 << 16);
        u16 b0 = f2b(w[3][px + 2] + gelu_f(acc1[px] + bsv));
        u16 b1 = f2b(w[3][px + 3] + gelu_f(acc1[px + 1] + bsv));
        o1[px >> 1] = (u32)b0 | ((u32)b1 << 16);
    }
    *(uint4*)(dst + y * WW + xb) = *(uint4*)o0;
    *(uint4*)(dst + (y + 1) * WW + xb) = *(uint4*)o1;
}

extern "C" void kernel_launch(void* const* d_in, const int* in_sizes, int n_in,
                              void* d_out, int out_size, void* d_ws, size_t ws_size,
                              hipStream_t stream) {
    const float* x       = (const float*)d_in[0];
    const float* means   = (const float*)d_in[1];
    const float* ln1_w   = (const float*)d_in[2];
    const float* ln1_b   = (const float*)d_in[3];
    const float* wq      = (const float*)d_in[4];
    const float* wk      = (const float*)d_in[5];
    const float* wv      = (const float*)d_in[6];
    const float* wproj   = (const float*)d_in[7];
    const float* irca_wk = (const float*)d_in[8];
    const float* irca_wv = (const float*)d_in[9];
    const float* conv1w  = (const float*)d_in[10];
    const float* ln2_w   = (const float*)d_in[11];
    const float* ln2_b   = (const float*)d_in[12];
    const float* fc1_w   = (const float*)d_in[13];
    const float* fc1_b   = (const float*)d_in[14];
    const float* dw_w    = (const float*)d_in[15];
    const float* dw_b    = (const float*)d_in[16];
    const float* fc2_w   = (const float*)d_in[17];
    const float* fc2_b   = (const float*)d_in[18];
    float* out = (float*)d_out;

    const size_t need = 202514432;
    if (ws_size < need) return;

    char* base = (char*)d_ws;
    float* mhat  = (float*)(base);                 // 4096 B
    u16*   kgbb  = (u16*)(base + 4096);            // 2048 B
    u16*   vgtb  = (u16*)(base + 6144);            // 2048 B
    int*   bucket = (int*)(base + 8192);           // 524288 B (weights+iinv overlay after sort)
    u16*   wqkv  = (u16*)(base + 8192);            // 98304 B (wq|wk|wv stacked)
    u16*   wfub  = wqkv + 3 * 16384;               // 32768 B
    u16*   fc1b  = wfub + 16384;                   // 65536 B
    u16*   fc2b  = fc1b + 32768;                   // 65536 B
    u16*   iinv  = (u16*)(base + 270336);          // 262144 B (hole after fc2b, inside dead bucket)
    int*   cnt   = (int*)(base + 532480);
    int*   cbase = (int*)(base + 598016);
    int*   gidx  = (int*)(base + 663552);
    u16*   Abase = (u16*)(base + 1187840);         // 100663296 B: qkv -> {himg, xmb}
    u16*   x2b   = (u16*)(base + 101851136);       // 33554432 B
    u16*   dsum  = (u16*)(base + 135405568);       // 67108864 B

    u16* qkv  = Abase;                 // [B][NTOK][384]
    u16* himg = Abase;                 // [B][256][NTOK] (after qkv dead)
    u16* xmb  = Abase + 2 * BIG;       // [B][NTOK][128]
    u16* xnb   = (u16*)d_out;          // LN1 out (d_out scratch)
    u16* attnb = (u16*)d_out;          // attention out, SORTED order (overwrites xnb)

    k_prep<<<NTm, 128, 0, stream>>>(means, irca_wk, irca_wv, mhat, kgbb, vgtb);
    k_ln1<<<BB * NTOK / 64, 256, 0, stream>>>(x, ln1_w, ln1_b, mhat, xnb, bucket);
    k_count<<<BB * NTOK / 64, 64, 0, stream>>>(bucket, cnt);
    k_scan<<<BB, 64, 0, stream>>>(cnt, cbase);
    k_place<<<BB * NTOK / 64, 64, 0, stream>>>(bucket, cbase, gidx);
    k_inv<<<BB * NTOK / 256, 256, 0, stream>>>(gidx, iinv);

    // weight conversions (bucket region is dead now)
    k_cvtall<<<448, 256, 0, stream>>>(wq, wk, wv, fc1_w, fc2_w, wqkv, fc1b, fc2b);
    k_fuse<<<64, 256, 0, stream>>>(conv1w, wproj, wfub);

    // q prescale includes log2(e): attn softmax uses raw v_exp_f32 (2^x)
    const float qsc2 = 0.25503489924160945f;  // (1/sqrt(32)) * log2(e)
    // fused gathered QKV: [B][NTOK][384]
    g_mfma<128, 384, 1, 0, 0, 0, 0, 0, 1, 0><<<dim3(128, 3, BB), 256, 0, stream>>>(
        xnb, wqkv, nullptr, nullptr, gidx, qkv, qsc2, nullptr, nullptr, nullptr);

    k_attn<<<dim3(NGRP, 2, BB), 256, 0, stream>>>(qkv, kgbb, vgtb, attnb);

    // x2 = x_img + gather(attn_sorted, iinv) @ Wfused^T, fused LN2:
    // writes x2b AND xmb (bf16 token)
    g_mfma<128, 128, 2, 0, 0, 0, 1, 0, 1, 1><<<dim3(128, 1, BB), 256, 0, stream>>>(
        attnb, wfub, nullptr, x, (const int*)iinv, x2b, 1.0f, ln2_w, ln2_b, xmb);

    g_mfma<128, 256, 0, 0, 1, 1, 0, 1, 1, 0><<<dim3(128, 2, BB), 256, 0, stream>>>(
        xmb, fc1b, fc1_b, nullptr, nullptr, himg, 1.0f, nullptr, nullptr, nullptr);
    k_dw<<<dim3(4, MLPD, BB), 256, 0, stream>>>(himg, dw_w, dw_b, dsum);
    // fc2 from image-layout dsum, + bf16 token resid x2, fp32 image out
    g_mfma<256, 128, 0, 1, 1, 0, 3, 1, 0, 0><<<dim3(128, 1, BB), 256, 0, stream>>>(
        dsum, fc2b, fc2_b, x2b, nullptr, out, 1.0f, nullptr, nullptr, nullptr);

    (void)in_sizes; (void)n_in; (void)out_size;
}